// Round 10
// baseline (514.584 us; speedup 1.0000x reference)
//
#include <hip/hip_runtime.h>

#define B_ 64
#define L_ 1024
#define D_ 64
#define QT 16

typedef _Float16 f16;
typedef __attribute__((ext_vector_type(8))) _Float16 f16x8;
typedef __attribute__((ext_vector_type(4))) _Float16 f16x4;
typedef __attribute__((ext_vector_type(4))) float f32x4;

// workspace layout (bytes)
#define WS_KH 0u
#define WS_KL 8388608u
#define WS_VT 16777216u
#define WS_NEED 25165824u

#define MFMA16(A, B, C) __builtin_amdgcn_mfma_f32_16x16x32_f16((A), (B), (C), 0, 0, 0)

// ---------------- combined prep kernel ----------------
// blocks [0,2048): K*0.125 -> hi/lo f16 ; blocks [2048,3072): V -> Vt[b][d][k] f16
__global__ __launch_bounds__(256)
void prep_kv(const float* __restrict__ kk, const float* __restrict__ v,
             f16* __restrict__ kh, f16* __restrict__ kl, f16* __restrict__ vt) {
    __shared__ f16 tile[64][72];
    if (blockIdx.x < 2048) {
        const int i = (blockIdx.x * 256 + threadIdx.x) * 8;
        float4 f0 = *(const float4*)(kk + i);
        float4 f1 = *(const float4*)(kk + i + 4);
        float fv[8] = {f0.x, f0.y, f0.z, f0.w, f1.x, f1.y, f1.z, f1.w};
        f16x8 h, lo;
        #pragma unroll
        for (int j = 0; j < 8; ++j) {
            float x = fv[j] * 0.125f;
            f16 hh = (f16)x;
            h[j] = hh;
            lo[j] = (f16)(x - (float)hh);
        }
        *(f16x8*)(kh + i) = h;
        *(f16x8*)(kl + i) = lo;
    } else {
        const int bb = blockIdx.x - 2048;
        const int b = bb >> 4, kt = bb & 15;
        const int r = threadIdx.x >> 2, c0 = (threadIdx.x & 3) * 16;
        const float* vp = v + (size_t)(b * L_ + kt * 64 + r) * D_ + c0;
        float4 g0 = *(const float4*)vp;
        float4 g1 = *(const float4*)(vp + 4);
        float4 g2 = *(const float4*)(vp + 8);
        float4 g3 = *(const float4*)(vp + 12);
        float fv[16] = {g0.x, g0.y, g0.z, g0.w, g1.x, g1.y, g1.z, g1.w,
                        g2.x, g2.y, g2.z, g2.w, g3.x, g3.y, g3.z, g3.w};
        #pragma unroll
        for (int j = 0; j < 16; ++j) tile[r][c0 + j] = (f16)fv[j];
        __syncthreads();
        f16x8 o0, o1;
        #pragma unroll
        for (int j = 0; j < 8; ++j) { o0[j] = tile[c0 + j][r]; o1[j] = tile[c0 + 8 + j][r]; }
        f16* op = vt + (size_t)(b * 64 + r) * 1024 + kt * 64 + c0;
        *(f16x8*)op = o0;
        *(f16x8*)(op + 8) = o1;
    }
}

// ---------------- main body: persistent blocks, 4 q-tiles each ----------------
// Swapped QK^T: mfma(A=K-frag, B=Q-frag) -> lane owns (q=lr, k=kq+c*16+lg*4+{0..3}).
// Mask ring depth 8 (~8 chunks ~1000+ cy of cover vs ~900 cy HBM latency).
// attn stores of iter i drain under iter i+1's QK^T (persistent loop).

template<bool E4>
__device__ __forceinline__ void sdpa_body(
    const float* __restrict__ q, const f16* __restrict__ kh,
    const f16* __restrict__ kl, const f16* __restrict__ vt,
    const unsigned char* __restrict__ mask,
    float* __restrict__ out, float* __restrict__ attn,
    f16* __restrict__ ST, float (*wsumP)[QT], float* __restrict__ OL)
{
    const int tid = threadIdx.x;
    const int l = tid & 63, w = tid >> 6;
    const int lr = l & 15, lg = l >> 4;
    const int bid0 = blockIdx.x;
    const int bid = (bid0 & 7) * 128 + (bid0 >> 3);   // XCD swizzle (1024 % 8 == 0, bijective)
    const int kq = w * 256;
    const int wbase = w * 4096;              // f16 units; 8 KB staging per wave
    const int swx = (lr & 7) << 3;           // XOR swizzle (f16-index bits 3..5)

    const int b = (bid * 4) >> 6;            // all 4 tiles of a block share the batch
    const f16* khp = kh + (size_t)(b * L_ + kq + lr) * D_ + lg * 8;
    const f16* klp = kl + (size_t)(b * L_ + kq + lr) * D_ + lg * 8;
    const f16* vtb = vt + (size_t)b * 64 * 1024 + kq + lg * 8;

    for (int it = 0; it < 4; ++it) {
        const int tile = bid * 4 + it;
        const int qt = tile & 63;
        const int qbase = b * L_ + qt * QT;

        // ---- Q frags hi/lo for this tile ----
        f16x8 aqh0, aqh1, aql0, aql1;
        {
            const float* qp = q + (size_t)(qbase + lr) * D_;
            float4 f0 = *(const float4*)(qp + lg * 8);
            float4 f1 = *(const float4*)(qp + lg * 8 + 4);
            float4 f2 = *(const float4*)(qp + 32 + lg * 8);
            float4 f3 = *(const float4*)(qp + 32 + lg * 8 + 4);
            float fa[8] = {f0.x, f0.y, f0.z, f0.w, f1.x, f1.y, f1.z, f1.w};
            float fb[8] = {f2.x, f2.y, f2.z, f2.w, f3.x, f3.y, f3.z, f3.w};
            #pragma unroll
            for (int j = 0; j < 8; ++j) {
                f16 h = (f16)fa[j]; aqh0[j] = h; aql0[j] = (f16)(fa[j] - (float)h);
                h = (f16)fb[j];     aqh1[j] = h; aql1[j] = (f16)(fb[j] - (float)h);
            }
        }

        // ---- mask ring, depth 8 ----
        const size_t mrow = (size_t)(qbase + lr) * L_ + kq + lg * 4;
        int4 mq[8]; uchar4 mu[8];
        #pragma unroll
        for (int t = 0; t < 8; ++t) {
            if (E4) mq[t] = *(const int4*)((const int*)mask + mrow + t * 16);
            else    mu[t] = *(const uchar4*)(mask + mrow + t * 16);
        }

        // ---- phase A: swapped QK^T -> e = mask ? 0 : exp(s) -> staging ----
        f16x8 kc0 = *(const f16x8*)khp, kc1 = *(const f16x8*)(khp + 32);
        f16x8 lc0 = *(const f16x8*)klp, lc1 = *(const f16x8*)(klp + 32);
        float rsum = 0.f;
        #pragma unroll
        for (int c = 0; c < 16; ++c) {
            f16x8 kn0, kn1, ln0, ln1;
            if (c < 15) {
                const f16* p1 = khp + (c + 1) * 1024;
                const f16* p2 = klp + (c + 1) * 1024;
                kn0 = *(const f16x8*)p1; kn1 = *(const f16x8*)(p1 + 32);
                ln0 = *(const f16x8*)p2; ln1 = *(const f16x8*)(p2 + 32);
            }
            // 3 independent 2-MFMA chains
            f32x4 aA = {0.f,0.f,0.f,0.f}, aB = {0.f,0.f,0.f,0.f}, aC = {0.f,0.f,0.f,0.f};
            aA = MFMA16(kc0, aqh0, aA); aA = MFMA16(kc1, aqh1, aA);
            aB = MFMA16(kc0, aql0, aB); aB = MFMA16(kc1, aql1, aB);
            aC = MFMA16(lc0, aqh0, aC); aC = MFMA16(lc1, aqh1, aC);
            int mm[4];
            if (E4) { mm[0] = mq[c & 7].x; mm[1] = mq[c & 7].y;
                      mm[2] = mq[c & 7].z; mm[3] = mq[c & 7].w; }
            else    { mm[0] = mu[c & 7].x; mm[1] = mu[c & 7].y;
                      mm[2] = mu[c & 7].z; mm[3] = mu[c & 7].w; }
            if (c + 8 < 16) {              // reissue ring slot (stays 8 ahead)
                if (E4) mq[c & 7] = *(const int4*)((const int*)mask + mrow + (c + 8) * 16);
                else    mu[c & 7] = *(const uchar4*)(mask + mrow + (c + 8) * 16);
            }
            f16x4 qd;
            #pragma unroll
            for (int r = 0; r < 4; ++r) {
                float e = mm[r] ? 0.f : __expf(aA[r] + aB[r] + aC[r]);  // |s|<~7
                rsum += e;
                qd[r] = (f16)e;
            }
            *(f16x4*)&ST[(wbase + lr * 256 + c * 16 + lg * 4) ^ swx] = qd;
            if (c < 15) { kc0 = kn0; kc1 = kn1; lc0 = ln0; lc1 = ln1; }
        }

        // ---- wave-local fence, gather PV A-frags ----
        asm volatile("s_waitcnt lgkmcnt(0)" ::: "memory");
        __builtin_amdgcn_sched_barrier(0);
        f16x8 pa[8];
        #pragma unroll
        for (int t = 0; t < 8; ++t)
            pa[t] = *(const f16x8*)&ST[(wbase + lr * 256 + t * 32 + lg * 8) ^ swx];

        rsum += __shfl_xor(rsum, 16);
        rsum += __shfl_xor(rsum, 32);
        if (l < 16) wsumP[w][lr] = rsum;
        __syncthreads();                    // bar1: wsumP ready; staging dead -> OL may reuse

        const float inv = 1.0f / (wsumP[0][lr] + wsumP[1][lr] + wsumP[2][lr] + wsumP[3][lr]);

        // ---- phase C: attn stores (fire-and-forget) interleaved with PV ----
        float* ap = attn + (size_t)(qbase + lr) * L_ + kq + lg * 8;
        f32x4 acc4[4] = {{0,0,0,0},{0,0,0,0},{0,0,0,0},{0,0,0,0}};
        f16x8 bc[4];
        #pragma unroll
        for (int nt = 0; nt < 4; ++nt)
            bc[nt] = *(const f16x8*)(vtb + (size_t)(nt * 16 + lr) * 1024);

        #pragma unroll
        for (int t = 0; t < 8; ++t) {
            f16x8 bn[4];
            if (t < 7) {
                #pragma unroll
                for (int nt = 0; nt < 4; ++nt)
                    bn[nt] = *(const f16x8*)(vtb + (size_t)(nt * 16 + lr) * 1024 + (t + 1) * 32);
            }
            f32x4 p0, p1;
            p0[0] = (float)pa[t][0] * inv; p0[1] = (float)pa[t][1] * inv;
            p0[2] = (float)pa[t][2] * inv; p0[3] = (float)pa[t][3] * inv;
            p1[0] = (float)pa[t][4] * inv; p1[1] = (float)pa[t][5] * inv;
            p1[2] = (float)pa[t][6] * inv; p1[3] = (float)pa[t][7] * inv;
            *(f32x4*)(ap + t * 32)     = p0;
            *(f32x4*)(ap + t * 32 + 4) = p1;
            #pragma unroll
            for (int nt = 0; nt < 4; ++nt)
                acc4[nt] = MFMA16(pa[t], bc[nt], acc4[nt]);
            if (t < 7) {
                #pragma unroll
                for (int nt = 0; nt < 4; ++nt) bc[nt] = bn[nt];
            }
        }

        // ---- cross-wave O reduction (OL aliases staging; fenced by bar1/bar3) ----
        #pragma unroll
        for (int nt = 0; nt < 4; ++nt) {
            #pragma unroll
            for (int r = 0; r < 4; ++r)
                OL[w * (16 * 68) + (lg * 4 + r) * 68 + nt * 16 + lr] = acc4[nt][r];
        }
        __syncthreads();                    // bar2
        {
            const int row = tid >> 4, c4 = (tid & 15) * 4;
            f32x4 o = {0.f, 0.f, 0.f, 0.f};
            #pragma unroll
            for (int ww = 0; ww < 4; ++ww) {
                const float* p = &OL[ww * (16 * 68) + row * 68 + c4];
                o[0] += p[0]; o[1] += p[1]; o[2] += p[2]; o[3] += p[3];
            }
            const float invr = 1.0f / (wsumP[0][row] + wsumP[1][row] +
                                       wsumP[2][row] + wsumP[3][row]);
            f32x4 r = {o[0] * invr, o[1] * invr, o[2] * invr, o[3] * invr};
            *(f32x4*)(out + (size_t)(qbase + row) * D_ + c4) = r;
        }
        __syncthreads();                    // bar3: OL reads done -> staging reusable
    }
}

__global__ __launch_bounds__(256, 4)
void sdpa_main(const float* __restrict__ q, const f16* __restrict__ kh,
               const f16* __restrict__ kl, const f16* __restrict__ vt,
               const unsigned char* __restrict__ mask,
               float* __restrict__ out, float* __restrict__ attn)
{
    __shared__ __align__(16) char smem[32768];   // staging (4 waves x 8 KB) <-> OL (17.4 KB)
    __shared__ float wsumP[4][QT];

    // runtime mask element-width detection (deterministic, uniform)
    unsigned det = 0;
    {
        const unsigned* mw = (const unsigned*)mask;
        #pragma unroll
        for (int i = 0; i < 32; ++i) det |= mw[i];
    }
    const bool elem4 = (det <= 1u) || (det == 0x3F800000u);

    if (elem4)
        sdpa_body<true>(q, kh, kl, vt, mask, out, attn, (f16*)smem, wsumP, (float*)smem);
    else
        sdpa_body<false>(q, kh, kl, vt, mask, out, attn, (f16*)smem, wsumP, (float*)smem);
}

// ---------------- fallback (round-3 kernel, used if ws too small) ----------------

__device__ __forceinline__ int sidx(int row, int col) {
    return row * 1024 + ((((col >> 3) ^ (row & 7)) << 3) | (col & 7));
}

__global__ __launch_bounds__(256, 4)
void sdpa_fallback(const float* __restrict__ q, const float* __restrict__ kk,
                   const float* __restrict__ v, const unsigned char* __restrict__ mask,
                   float* __restrict__ out, float* __restrict__ attn)
{
    __shared__ f16 S[QT * 1024];
    __shared__ float wmax[4][QT];
    __shared__ float wsum[QT];

    const int tid = threadIdx.x;
    const int l = tid & 63, w = tid >> 6;
    const int lr = l & 15, lg = l >> 4;
    const int bid = blockIdx.x;
    const int b = bid >> 6, qt = bid & 63;
    const int qbase = b * L_ + qt * QT;

    unsigned det = 0;
    {
        const unsigned* mw = (const unsigned*)mask;
        #pragma unroll
        for (int i = 0; i < 32; ++i) det |= mw[i];
    }
    const bool elem4 = (det <= 1u) || (det == 0x3F800000u);

    f16x8 aqh[2], aql[2];
    {
        const float* qp = q + (size_t)(qbase + lr) * D_;
        #pragma unroll
        for (int s = 0; s < 2; ++s) {
            float4 f0 = *(const float4*)(qp + s * 32 + lg * 8);
            float4 f1 = *(const float4*)(qp + s * 32 + lg * 8 + 4);
            float fv[8] = {f0.x, f0.y, f0.z, f0.w, f1.x, f1.y, f1.z, f1.w};
            #pragma unroll
            for (int j = 0; j < 8; ++j) {
                f16 h = (f16)fv[j];
                aqh[s][j] = h;
                aql[s][j] = (f16)(fv[j] - (float)h);
            }
        }
    }

    float vmax[4] = {-INFINITY, -INFINITY, -INFINITY, -INFINITY};
    const float* kb = kk + (size_t)(b * L_ + w * 16 + lr) * D_ + lg * 8;
    const size_t mrowbase = (size_t)(qbase + lg * 4) * L_ + w * 16 + lr;

    float4 kc[4];
    kc[0] = *(const float4*)kb;
    kc[1] = *(const float4*)(kb + 4);
    kc[2] = *(const float4*)(kb + 32);
    kc[3] = *(const float4*)(kb + 36);
    int mcur[4], mnxt[4];
    #pragma unroll
    for (int r2 = 0; r2 < 4; ++r2) {
        if (elem4) {
            mcur[r2] = ((const int*)mask)[mrowbase + (size_t)r2 * L_];
            mnxt[r2] = ((const int*)mask)[mrowbase + (size_t)r2 * L_ + 64];
        } else {
            mcur[r2] = mask[mrowbase + (size_t)r2 * L_];
            mnxt[r2] = mask[mrowbase + (size_t)r2 * L_ + 64];
        }
    }

    for (int ck = 0; ck < 16; ++ck) {
        float4 kn[4];
        if (ck < 15) {
            const float* kp = kb + (size_t)(ck + 1) * 64 * D_;
            kn[0] = *(const float4*)kp;
            kn[1] = *(const float4*)(kp + 4);
            kn[2] = *(const float4*)(kp + 32);
            kn[3] = *(const float4*)(kp + 36);
        }
        int mfut[4];
        if (ck < 14) {
            const size_t mo = mrowbase + (size_t)(ck + 2) * 64;
            if (elem4) {
                #pragma unroll
                for (int r2 = 0; r2 < 4; ++r2) mfut[r2] = ((const int*)mask)[mo + (size_t)r2 * L_];
            } else {
                #pragma unroll
                for (int r2 = 0; r2 < 4; ++r2) mfut[r2] = mask[mo + (size_t)r2 * L_];
            }
        }
        f16x8 bh[2], bl[2];
        #pragma unroll
        for (int s = 0; s < 2; ++s) {
            float fv[8] = {kc[2*s].x, kc[2*s].y, kc[2*s].z, kc[2*s].w,
                           kc[2*s+1].x, kc[2*s+1].y, kc[2*s+1].z, kc[2*s+1].w};
            #pragma unroll
            for (int j = 0; j < 8; ++j) {
                f16 h = (f16)fv[j];
                bh[s][j] = h;
                bl[s][j] = (f16)(fv[j] - (float)h);
            }
        }
        f32x4 acc = {0.f, 0.f, 0.f, 0.f};
        #pragma unroll
        for (int s = 0; s < 2; ++s) {
            acc = MFMA16(aqh[s], bh[s], acc);
            acc = MFMA16(aql[s], bh[s], acc);
            acc = MFMA16(aqh[s], bl[s], acc);
        }
        const int scol = ck * 64 + w * 16 + lr;
        #pragma unroll
        for (int r2 = 0; r2 < 4; ++r2) {
            float sv = mcur[r2] ? -INFINITY : acc[r2] * 0.125f;
            S[sidx(lg * 4 + r2, scol)] = (f16)sv;
            vmax[r2] = fmaxf(vmax[r2], sv);
        }
        #pragma unroll
        for (int r2 = 0; r2 < 4; ++r2) mcur[r2] = mnxt[r2];
        if (ck < 14) {
            #pragma unroll
            for (int r2 = 0; r2 < 4; ++r2) mnxt[r2] = mfut[r2];
        }
        if (ck < 15) {
            #pragma unroll
            for (int j = 0; j < 4; ++j) kc[j] = kn[j];
        }
    }
    #pragma unroll
    for (int r2 = 0; r2 < 4; ++r2) {
        #pragma unroll
        for (int off = 1; off < 16; off <<= 1)
            vmax[r2] = fmaxf(vmax[r2], __shfl_xor(vmax[r2], off));
    }
    if (lr == 0) {
        #pragma unroll
        for (int r2 = 0; r2 < 4; ++r2) wmax[w][lg * 4 + r2] = vmax[r2];
    }
    __syncthreads();

    {
        const int row = tid >> 4, cg = tid & 15;
        const float m = fmaxf(fmaxf(wmax[0][row], wmax[1][row]),
                              fmaxf(wmax[2][row], wmax[3][row]));
        float sum = 0.f;
        #pragma unroll
        for (int c = 0; c < 8; ++c) {
            f16* sp = &S[row * 1024 + (((cg + 16 * c) ^ (row & 7)) << 3)];
            f16x8 sv = *(const f16x8*)sp;
            f16x8 evv;
            #pragma unroll
            for (int j = 0; j < 8; ++j) {
                float e = __expf((float)sv[j] - m);
                evv[j] = (f16)e;
                sum += e;
            }
            *(f16x8*)sp = evv;
        }
        #pragma unroll
        for (int off = 1; off < 16; off <<= 1) sum += __shfl_xor(sum, off);
        if (cg == 0) wsum[row] = sum;
        __syncthreads();

        const float inv = 1.0f / wsum[row];
        float* ap = attn + (size_t)(qbase + row) * L_;
        #pragma unroll
        for (int c = 0; c < 8; ++c) {
            f16x8 evv = *(const f16x8*)&S[row * 1024 + (((cg + 16 * c) ^ (row & 7)) << 3)];
            float4 p0, p1;
            p0.x = (float)evv[0] * inv; p0.y = (float)evv[1] * inv;
            p0.z = (float)evv[2] * inv; p0.w = (float)evv[3] * inv;
            p1.x = (float)evv[4] * inv; p1.y = (float)evv[5] * inv;
            p1.z = (float)evv[6] * inv; p1.w = (float)evv[7] * inv;
            *(float4*)(ap + (cg + 16 * c) * 8)     = p0;
            *(float4*)(ap + (cg + 16 * c) * 8 + 4) = p1;
        }
    }

    f32x4 acc2 = {0.f, 0.f, 0.f, 0.f};
    const float* vb = v + (size_t)(b * L_) * D_ + w * 16 + lr;
    float vcA[8], vcB[8];
    #pragma unroll
    for (int j = 0; j < 8; ++j) {
        vcA[j] = vb[(size_t)(lg * 8 + j) * D_];
        vcB[j] = vb[(size_t)(32 + lg * 8 + j) * D_];
    }
    for (int tt = 0; tt < 16; ++tt) {
        {
            f16x8 pa = *(const f16x8*)&S[lr * 1024 + ((((2 * tt) * 4 + lg) ^ (lr & 7)) << 3)];
            f16x8 bv;
            #pragma unroll
            for (int j = 0; j < 8; ++j) bv[j] = (f16)vcA[j];
            if (tt < 15) {
                const float* vp = vb + (size_t)((2 * tt + 2) * 32 + lg * 8) * D_;
                #pragma unroll
                for (int j = 0; j < 8; ++j) vcA[j] = vp[(size_t)j * D_];
            }
            acc2 = MFMA16(pa, bv, acc2);
        }
        {
            f16x8 pa = *(const f16x8*)&S[lr * 1024 + ((((2 * tt + 1) * 4 + lg) ^ (lr & 7)) << 3)];
            f16x8 bv;
            #pragma unroll
            for (int j = 0; j < 8; ++j) bv[j] = (f16)vcB[j];
            if (tt < 15) {
                const float* vp = vb + (size_t)((2 * tt + 3) * 32 + lg * 8) * D_;
                #pragma unroll
                for (int j = 0; j < 8; ++j) vcB[j] = vp[(size_t)j * D_];
            }
            acc2 = MFMA16(pa, bv, acc2);
        }
    }

    #pragma unroll
    for (int r2 = 0; r2 < 4; ++r2) {
        const float invr = 1.0f / wsum[lg * 4 + r2];
        out[(size_t)(qbase + lg * 4 + r2) * D_ + w * 16 + lr] = acc2[r2] * invr;
    }
}

extern "C" void kernel_launch(void* const* d_in, const int* in_sizes, int n_in,
                              void* d_out, int out_size, void* d_ws, size_t ws_size,
                              hipStream_t stream) {
    const float* q = (const float*)d_in[0];
    const float* k = (const float*)d_in[1];
    const float* v = (const float*)d_in[2];
    const unsigned char* mask = (const unsigned char*)d_in[3];
    float* out = (float*)d_out;
    float* attn = out + (size_t)B_ * L_ * D_;

    if (ws_size >= (size_t)WS_NEED) {
        f16* kh = (f16*)((char*)d_ws + WS_KH);
        f16* kl = (f16*)((char*)d_ws + WS_KL);
        f16* vt = (f16*)((char*)d_ws + WS_VT);
        prep_kv<<<dim3(3072), 256, 0, stream>>>(k, v, kh, kl, vt);
        sdpa_main<<<dim3(1024), 256, 0, stream>>>(q, kh, kl, vt, mask, out, attn);
    } else {
        sdpa_fallback<<<dim3(B_ * (L_ / QT)), 256, 0, stream>>>(q, k, v, mask, out, attn);
    }
}

// Round 11
// 395.226 us; speedup vs baseline: 1.3020x; 1.3020x over previous
//
#include <hip/hip_runtime.h>

#define B_ 64
#define L_ 1024
#define D_ 64
#define QT 16

typedef _Float16 f16;
typedef __attribute__((ext_vector_type(8))) _Float16 f16x8;
typedef __attribute__((ext_vector_type(4))) _Float16 f16x4;
typedef __attribute__((ext_vector_type(4))) float f32x4;

// workspace layout (bytes)
#define WS_KH 0u
#define WS_KL 8388608u
#define WS_VT 16777216u
#define WS_NEED 25165824u

#define MFMA16(A, B, C) __builtin_amdgcn_mfma_f32_16x16x32_f16((A), (B), (C), 0, 0, 0)

// ---------------- combined prep kernel ----------------
// blocks [0,2048): K*0.125 -> hi/lo f16 ; blocks [2048,3072): V -> Vt[b][d][k] f16
__global__ __launch_bounds__(256)
void prep_kv(const float* __restrict__ kk, const float* __restrict__ v,
             f16* __restrict__ kh, f16* __restrict__ kl, f16* __restrict__ vt) {
    __shared__ f16 tile[64][72];
    if (blockIdx.x < 2048) {
        const int i = (blockIdx.x * 256 + threadIdx.x) * 8;
        float4 f0 = *(const float4*)(kk + i);
        float4 f1 = *(const float4*)(kk + i + 4);
        float fv[8] = {f0.x, f0.y, f0.z, f0.w, f1.x, f1.y, f1.z, f1.w};
        f16x8 h, lo;
        #pragma unroll
        for (int j = 0; j < 8; ++j) {
            float x = fv[j] * 0.125f;
            f16 hh = (f16)x;
            h[j] = hh;
            lo[j] = (f16)(x - (float)hh);
        }
        *(f16x8*)(kh + i) = h;
        *(f16x8*)(kl + i) = lo;
    } else {
        const int bb = blockIdx.x - 2048;
        const int b = bb >> 4, kt = bb & 15;
        const int r = threadIdx.x >> 2, c0 = (threadIdx.x & 3) * 16;
        const float* vp = v + (size_t)(b * L_ + kt * 64 + r) * D_ + c0;
        float4 g0 = *(const float4*)vp;
        float4 g1 = *(const float4*)(vp + 4);
        float4 g2 = *(const float4*)(vp + 8);
        float4 g3 = *(const float4*)(vp + 12);
        float fv[16] = {g0.x, g0.y, g0.z, g0.w, g1.x, g1.y, g1.z, g1.w,
                        g2.x, g2.y, g2.z, g2.w, g3.x, g3.y, g3.z, g3.w};
        #pragma unroll
        for (int j = 0; j < 16; ++j) tile[r][c0 + j] = (f16)fv[j];
        __syncthreads();
        f16x8 o0, o1;
        #pragma unroll
        for (int j = 0; j < 8; ++j) { o0[j] = tile[c0 + j][r]; o1[j] = tile[c0 + 8 + j][r]; }
        f16* op = vt + (size_t)(b * 64 + r) * 1024 + kt * 64 + c0;
        *(f16x8*)op = o0;
        *(f16x8*)(op + 8) = o1;
    }
}

// ---------------- main body: persistent blocks, 4 q-tiles each ----------------
// Swapped QK^T: mfma(A=K-frag, B=Q-frag) -> lane owns (q=lr, k=kq+c*16+lg*4+{0..3}).
// Mask ring depth 8 (~8 chunks of cover vs ~900 cy HBM latency).
// attn stores of iter i drain under iter i+1's QK^T (persistent loop).

template<bool E4>
__device__ __forceinline__ void sdpa_body(
    const float* __restrict__ q, const f16* __restrict__ kh,
    const f16* __restrict__ kl, const f16* __restrict__ vt,
    const unsigned char* __restrict__ mask,
    float* __restrict__ out, float* __restrict__ attn,
    f16* __restrict__ ST, float (*wsumP)[QT], float* __restrict__ OL)
{
    const int tid = threadIdx.x;
    const int l = tid & 63, w = tid >> 6;
    const int lr = l & 15, lg = l >> 4;
    const int bid0 = blockIdx.x;
    const int bid = (bid0 & 7) * 128 + (bid0 >> 3);   // XCD swizzle (1024 % 8 == 0, bijective)
    const int kq = w * 256;
    const int wbase = w * 4096;              // f16 units; 8 KB staging per wave
    const int swx = (lr & 7) << 3;           // XOR swizzle (f16-index bits 3..5)

    const int b = (bid * 4) >> 6;            // all 4 tiles of a block share the batch
    const f16* khp = kh + (size_t)(b * L_ + kq + lr) * D_ + lg * 8;
    const f16* klp = kl + (size_t)(b * L_ + kq + lr) * D_ + lg * 8;
    const f16* vtb = vt + (size_t)b * 64 * 1024 + kq + lg * 8;

    for (int it = 0; it < 4; ++it) {
        const int tile = bid * 4 + it;
        const int qt = tile & 63;
        const int qbase = b * L_ + qt * QT;

        // ---- Q frags hi/lo for this tile ----
        f16x8 aqh0, aqh1, aql0, aql1;
        {
            const float* qp = q + (size_t)(qbase + lr) * D_;
            float4 f0 = *(const float4*)(qp + lg * 8);
            float4 f1 = *(const float4*)(qp + lg * 8 + 4);
            float4 f2 = *(const float4*)(qp + 32 + lg * 8);
            float4 f3 = *(const float4*)(qp + 32 + lg * 8 + 4);
            float fa[8] = {f0.x, f0.y, f0.z, f0.w, f1.x, f1.y, f1.z, f1.w};
            float fb[8] = {f2.x, f2.y, f2.z, f2.w, f3.x, f3.y, f3.z, f3.w};
            #pragma unroll
            for (int j = 0; j < 8; ++j) {
                f16 h = (f16)fa[j]; aqh0[j] = h; aql0[j] = (f16)(fa[j] - (float)h);
                h = (f16)fb[j];     aqh1[j] = h; aql1[j] = (f16)(fb[j] - (float)h);
            }
        }

        // ---- mask ring, depth 8 ----
        const size_t mrow = (size_t)(qbase + lr) * L_ + kq + lg * 4;
        int4 mq[8]; uchar4 mu[8];
        #pragma unroll
        for (int t = 0; t < 8; ++t) {
            if (E4) mq[t] = *(const int4*)((const int*)mask + mrow + t * 16);
            else    mu[t] = *(const uchar4*)(mask + mrow + t * 16);
        }

        // ---- phase A: swapped QK^T -> e = mask ? 0 : exp(s) -> staging ----
        f16x8 kc0 = *(const f16x8*)khp, kc1 = *(const f16x8*)(khp + 32);
        f16x8 lc0 = *(const f16x8*)klp, lc1 = *(const f16x8*)(klp + 32);
        float rsum = 0.f;
        #pragma unroll
        for (int c = 0; c < 16; ++c) {
            f16x8 kn0, kn1, ln0, ln1;
            if (c < 15) {
                const f16* p1 = khp + (c + 1) * 1024;
                const f16* p2 = klp + (c + 1) * 1024;
                kn0 = *(const f16x8*)p1; kn1 = *(const f16x8*)(p1 + 32);
                ln0 = *(const f16x8*)p2; ln1 = *(const f16x8*)(p2 + 32);
            }
            // 3 independent 2-MFMA chains
            f32x4 aA = {0.f,0.f,0.f,0.f}, aB = {0.f,0.f,0.f,0.f}, aC = {0.f,0.f,0.f,0.f};
            aA = MFMA16(kc0, aqh0, aA); aA = MFMA16(kc1, aqh1, aA);
            aB = MFMA16(kc0, aql0, aB); aB = MFMA16(kc1, aql1, aB);
            aC = MFMA16(lc0, aqh0, aC); aC = MFMA16(lc1, aqh1, aC);
            int mm[4];
            if (E4) { mm[0] = mq[c & 7].x; mm[1] = mq[c & 7].y;
                      mm[2] = mq[c & 7].z; mm[3] = mq[c & 7].w; }
            else    { mm[0] = mu[c & 7].x; mm[1] = mu[c & 7].y;
                      mm[2] = mu[c & 7].z; mm[3] = mu[c & 7].w; }
            if (c + 8 < 16) {              // reissue ring slot (stays 8 ahead)
                if (E4) mq[c & 7] = *(const int4*)((const int*)mask + mrow + (c + 8) * 16);
                else    mu[c & 7] = *(const uchar4*)(mask + mrow + (c + 8) * 16);
            }
            f16x4 qd;
            #pragma unroll
            for (int r = 0; r < 4; ++r) {
                float e = mm[r] ? 0.f : __expf(aA[r] + aB[r] + aC[r]);  // |s|<~7
                rsum += e;
                qd[r] = (f16)e;
            }
            *(f16x4*)&ST[(wbase + lr * 256 + c * 16 + lg * 4) ^ swx] = qd;
            if (c < 15) { kc0 = kn0; kc1 = kn1; lc0 = ln0; lc1 = ln1; }
        }

        // ---- wave-local fence, gather PV A-frags ----
        asm volatile("s_waitcnt lgkmcnt(0)" ::: "memory");
        __builtin_amdgcn_sched_barrier(0);
        f16x8 pa[8];
        #pragma unroll
        for (int t = 0; t < 8; ++t)
            pa[t] = *(const f16x8*)&ST[(wbase + lr * 256 + t * 32 + lg * 8) ^ swx];

        rsum += __shfl_xor(rsum, 16);
        rsum += __shfl_xor(rsum, 32);
        if (l < 16) wsumP[w][lr] = rsum;
        __syncthreads();                    // bar1: wsumP ready; staging dead -> OL may reuse

        const float inv = 1.0f / (wsumP[0][lr] + wsumP[1][lr] + wsumP[2][lr] + wsumP[3][lr]);

        // ---- phase C: attn stores (fire-and-forget) interleaved with PV ----
        float* ap = attn + (size_t)(qbase + lr) * L_ + kq + lg * 8;
        f32x4 acc4[4] = {{0,0,0,0},{0,0,0,0},{0,0,0,0},{0,0,0,0}};
        f16x8 bc[4];
        #pragma unroll
        for (int nt = 0; nt < 4; ++nt)
            bc[nt] = *(const f16x8*)(vtb + (size_t)(nt * 16 + lr) * 1024);

        #pragma unroll
        for (int t = 0; t < 8; ++t) {
            f16x8 bn[4];
            if (t < 7) {
                #pragma unroll
                for (int nt = 0; nt < 4; ++nt)
                    bn[nt] = *(const f16x8*)(vtb + (size_t)(nt * 16 + lr) * 1024 + (t + 1) * 32);
            }
            f32x4 p0, p1;
            p0[0] = (float)pa[t][0] * inv; p0[1] = (float)pa[t][1] * inv;
            p0[2] = (float)pa[t][2] * inv; p0[3] = (float)pa[t][3] * inv;
            p1[0] = (float)pa[t][4] * inv; p1[1] = (float)pa[t][5] * inv;
            p1[2] = (float)pa[t][6] * inv; p1[3] = (float)pa[t][7] * inv;
            *(f32x4*)(ap + t * 32)     = p0;
            *(f32x4*)(ap + t * 32 + 4) = p1;
            #pragma unroll
            for (int nt = 0; nt < 4; ++nt)
                acc4[nt] = MFMA16(pa[t], bc[nt], acc4[nt]);
            if (t < 7) {
                #pragma unroll
                for (int nt = 0; nt < 4; ++nt) bc[nt] = bn[nt];
            }
        }

        // ---- cross-wave O reduction (OL aliases staging; fenced by bar1/bar3) ----
        #pragma unroll
        for (int nt = 0; nt < 4; ++nt) {
            #pragma unroll
            for (int r = 0; r < 4; ++r)
                OL[w * (16 * 68) + (lg * 4 + r) * 68 + nt * 16 + lr] = acc4[nt][r];
        }
        __syncthreads();                    // bar2
        {
            const int row = tid >> 4, c4 = (tid & 15) * 4;
            f32x4 o = {0.f, 0.f, 0.f, 0.f};
            #pragma unroll
            for (int ww = 0; ww < 4; ++ww) {
                const float* p = &OL[ww * (16 * 68) + row * 68 + c4];
                o[0] += p[0]; o[1] += p[1]; o[2] += p[2]; o[3] += p[3];
            }
            const float invr = 1.0f / (wsumP[0][row] + wsumP[1][row] +
                                       wsumP[2][row] + wsumP[3][row]);
            f32x4 r = {o[0] * invr, o[1] * invr, o[2] * invr, o[3] * invr};
            *(f32x4*)(out + (size_t)(qbase + row) * D_ + c4) = r;
        }
        __syncthreads();                    // bar3: OL reads done -> staging reusable
    }
}

// launch_bounds min-waves = 2: gives the allocator a 256-VGPR budget so the
// ring-8 + pa[8] live set (~110-120 regs) fits WITHOUT spilling to scratch.
// (R10 used min-waves=4; allocator pinned 64 VGPR and spilled ~690 MB to HBM.)
// Actual occupancy still ~4 waves/EU from the real register count.
__global__ __launch_bounds__(256, 2)
void sdpa_main(const float* __restrict__ q, const f16* __restrict__ kh,
               const f16* __restrict__ kl, const f16* __restrict__ vt,
               const unsigned char* __restrict__ mask,
               float* __restrict__ out, float* __restrict__ attn)
{
    __shared__ __align__(16) char smem[32768];   // staging (4 waves x 8 KB) <-> OL (17.4 KB)
    __shared__ float wsumP[4][QT];

    // runtime mask element-width detection (deterministic, uniform)
    unsigned det = 0;
    {
        const unsigned* mw = (const unsigned*)mask;
        #pragma unroll
        for (int i = 0; i < 32; ++i) det |= mw[i];
    }
    const bool elem4 = (det <= 1u) || (det == 0x3F800000u);

    if (elem4)
        sdpa_body<true>(q, kh, kl, vt, mask, out, attn, (f16*)smem, wsumP, (float*)smem);
    else
        sdpa_body<false>(q, kh, kl, vt, mask, out, attn, (f16*)smem, wsumP, (float*)smem);
}

// ---------------- fallback (round-3 kernel, used if ws too small) ----------------

__device__ __forceinline__ int sidx(int row, int col) {
    return row * 1024 + ((((col >> 3) ^ (row & 7)) << 3) | (col & 7));
}

__global__ __launch_bounds__(256, 4)
void sdpa_fallback(const float* __restrict__ q, const float* __restrict__ kk,
                   const float* __restrict__ v, const unsigned char* __restrict__ mask,
                   float* __restrict__ out, float* __restrict__ attn)
{
    __shared__ f16 S[QT * 1024];
    __shared__ float wmax[4][QT];
    __shared__ float wsum[QT];

    const int tid = threadIdx.x;
    const int l = tid & 63, w = tid >> 6;
    const int lr = l & 15, lg = l >> 4;
    const int bid = blockIdx.x;
    const int b = bid >> 6, qt = bid & 63;
    const int qbase = b * L_ + qt * QT;

    unsigned det = 0;
    {
        const unsigned* mw = (const unsigned*)mask;
        #pragma unroll
        for (int i = 0; i < 32; ++i) det |= mw[i];
    }
    const bool elem4 = (det <= 1u) || (det == 0x3F800000u);

    f16x8 aqh[2], aql[2];
    {
        const float* qp = q + (size_t)(qbase + lr) * D_;
        #pragma unroll
        for (int s = 0; s < 2; ++s) {
            float4 f0 = *(const float4*)(qp + s * 32 + lg * 8);
            float4 f1 = *(const float4*)(qp + s * 32 + lg * 8 + 4);
            float fv[8] = {f0.x, f0.y, f0.z, f0.w, f1.x, f1.y, f1.z, f1.w};
            #pragma unroll
            for (int j = 0; j < 8; ++j) {
                f16 h = (f16)fv[j];
                aqh[s][j] = h;
                aql[s][j] = (f16)(fv[j] - (float)h);
            }
        }
    }

    float vmax[4] = {-INFINITY, -INFINITY, -INFINITY, -INFINITY};
    const float* kb = kk + (size_t)(b * L_ + w * 16 + lr) * D_ + lg * 8;
    const size_t mrowbase = (size_t)(qbase + lg * 4) * L_ + w * 16 + lr;

    float4 kc[4];
    kc[0] = *(const float4*)kb;
    kc[1] = *(const float4*)(kb + 4);
    kc[2] = *(const float4*)(kb + 32);
    kc[3] = *(const float4*)(kb + 36);
    int mcur[4], mnxt[4];
    #pragma unroll
    for (int r2 = 0; r2 < 4; ++r2) {
        if (elem4) {
            mcur[r2] = ((const int*)mask)[mrowbase + (size_t)r2 * L_];
            mnxt[r2] = ((const int*)mask)[mrowbase + (size_t)r2 * L_ + 64];
        } else {
            mcur[r2] = mask[mrowbase + (size_t)r2 * L_];
            mnxt[r2] = mask[mrowbase + (size_t)r2 * L_ + 64];
        }
    }

    for (int ck = 0; ck < 16; ++ck) {
        float4 kn[4];
        if (ck < 15) {
            const float* kp = kb + (size_t)(ck + 1) * 64 * D_;
            kn[0] = *(const float4*)kp;
            kn[1] = *(const float4*)(kp + 4);
            kn[2] = *(const float4*)(kp + 32);
            kn[3] = *(const float4*)(kp + 36);
        }
        int mfut[4];
        if (ck < 14) {
            const size_t mo = mrowbase + (size_t)(ck + 2) * 64;
            if (elem4) {
                #pragma unroll
                for (int r2 = 0; r2 < 4; ++r2) mfut[r2] = ((const int*)mask)[mo + (size_t)r2 * L_];
            } else {
                #pragma unroll
                for (int r2 = 0; r2 < 4; ++r2) mfut[r2] = mask[mo + (size_t)r2 * L_];
            }
        }
        f16x8 bh[2], bl[2];
        #pragma unroll
        for (int s = 0; s < 2; ++s) {
            float fv[8] = {kc[2*s].x, kc[2*s].y, kc[2*s].z, kc[2*s].w,
                           kc[2*s+1].x, kc[2*s+1].y, kc[2*s+1].z, kc[2*s+1].w};
            #pragma unroll
            for (int j = 0; j < 8; ++j) {
                f16 h = (f16)fv[j];
                bh[s][j] = h;
                bl[s][j] = (f16)(fv[j] - (float)h);
            }
        }
        f32x4 acc = {0.f, 0.f, 0.f, 0.f};
        #pragma unroll
        for (int s = 0; s < 2; ++s) {
            acc = MFMA16(aqh[s], bh[s], acc);
            acc = MFMA16(aql[s], bh[s], acc);
            acc = MFMA16(aqh[s], bl[s], acc);
        }
        const int scol = ck * 64 + w * 16 + lr;
        #pragma unroll
        for (int r2 = 0; r2 < 4; ++r2) {
            float sv = mcur[r2] ? -INFINITY : acc[r2] * 0.125f;
            S[sidx(lg * 4 + r2, scol)] = (f16)sv;
            vmax[r2] = fmaxf(vmax[r2], sv);
        }
        #pragma unroll
        for (int r2 = 0; r2 < 4; ++r2) mcur[r2] = mnxt[r2];
        if (ck < 14) {
            #pragma unroll
            for (int r2 = 0; r2 < 4; ++r2) mnxt[r2] = mfut[r2];
        }
        if (ck < 15) {
            #pragma unroll
            for (int j = 0; j < 4; ++j) kc[j] = kn[j];
        }
    }
    #pragma unroll
    for (int r2 = 0; r2 < 4; ++r2) {
        #pragma unroll
        for (int off = 1; off < 16; off <<= 1)
            vmax[r2] = fmaxf(vmax[r2], __shfl_xor(vmax[r2], off));
    }
    if (lr == 0) {
        #pragma unroll
        for (int r2 = 0; r2 < 4; ++r2) wmax[w][lg * 4 + r2] = vmax[r2];
    }
    __syncthreads();

    {
        const int row = tid >> 4, cg = tid & 15;
        const float m = fmaxf(fmaxf(wmax[0][row], wmax[1][row]),
                              fmaxf(wmax[2][row], wmax[3][row]));
        float sum = 0.f;
        #pragma unroll
        for (int c = 0; c < 8; ++c) {
            f16* sp = &S[row * 1024 + (((cg + 16 * c) ^ (row & 7)) << 3)];
            f16x8 sv = *(const f16x8*)sp;
            f16x8 evv;
            #pragma unroll
            for (int j = 0; j < 8; ++j) {
                float e = __expf((float)sv[j] - m);
                evv[j] = (f16)e;
                sum += e;
            }
            *(f16x8*)sp = evv;
        }
        #pragma unroll
        for (int off = 1; off < 16; off <<= 1) sum += __shfl_xor(sum, off);
        if (cg == 0) wsum[row] = sum;
        __syncthreads();

        const float inv = 1.0f / wsum[row];
        float* ap = attn + (size_t)(qbase + row) * L_;
        #pragma unroll
        for (int c = 0; c < 8; ++c) {
            f16x8 evv = *(const f16x8*)&S[row * 1024 + (((cg + 16 * c) ^ (row & 7)) << 3)];
            float4 p0, p1;
            p0.x = (float)evv[0] * inv; p0.y = (float)evv[1] * inv;
            p0.z = (float)evv[2] * inv; p0.w = (float)evv[3] * inv;
            p1.x = (float)evv[4] * inv; p1.y = (float)evv[5] * inv;
            p1.z = (float)evv[6] * inv; p1.w = (float)evv[7] * inv;
            *(float4*)(ap + (cg + 16 * c) * 8)     = p0;
            *(float4*)(ap + (cg + 16 * c) * 8 + 4) = p1;
        }
    }

    f32x4 acc2 = {0.f, 0.f, 0.f, 0.f};
    const float* vb = v + (size_t)(b * L_) * D_ + w * 16 + lr;
    float vcA[8], vcB[8];
    #pragma unroll
    for (int j = 0; j < 8; ++j) {
        vcA[j] = vb[(size_t)(lg * 8 + j) * D_];
        vcB[j] = vb[(size_t)(32 + lg * 8 + j) * D_];
    }
    for (int tt = 0; tt < 16; ++tt) {
        {
            f16x8 pa = *(const f16x8*)&S[lr * 1024 + ((((2 * tt) * 4 + lg) ^ (lr & 7)) << 3)];
            f16x8 bv;
            #pragma unroll
            for (int j = 0; j < 8; ++j) bv[j] = (f16)vcA[j];
            if (tt < 15) {
                const float* vp = vb + (size_t)((2 * tt + 2) * 32 + lg * 8) * D_;
                #pragma unroll
                for (int j = 0; j < 8; ++j) vcA[j] = vp[(size_t)j * D_];
            }
            acc2 = MFMA16(pa, bv, acc2);
        }
        {
            f16x8 pa = *(const f16x8*)&S[lr * 1024 + ((((2 * tt + 1) * 4 + lg) ^ (lr & 7)) << 3)];
            f16x8 bv;
            #pragma unroll
            for (int j = 0; j < 8; ++j) bv[j] = (f16)vcB[j];
            if (tt < 15) {
                const float* vp = vb + (size_t)((2 * tt + 3) * 32 + lg * 8) * D_;
                #pragma unroll
                for (int j = 0; j < 8; ++j) vcB[j] = vp[(size_t)j * D_];
            }
            acc2 = MFMA16(pa, bv, acc2);
        }
    }

    #pragma unroll
    for (int r2 = 0; r2 < 4; ++r2) {
        const float invr = 1.0f / wsum[lg * 4 + r2];
        out[(size_t)(qbase + lg * 4 + r2) * D_ + w * 16 + lr] = acc2[r2] * invr;
    }
}

extern "C" void kernel_launch(void* const* d_in, const int* in_sizes, int n_in,
                              void* d_out, int out_size, void* d_ws, size_t ws_size,
                              hipStream_t stream) {
    const float* q = (const float*)d_in[0];
    const float* k = (const float*)d_in[1];
    const float* v = (const float*)d_in[2];
    const unsigned char* mask = (const unsigned char*)d_in[3];
    float* out = (float*)d_out;
    float* attn = out + (size_t)B_ * L_ * D_;

    if (ws_size >= (size_t)WS_NEED) {
        f16* kh = (f16*)((char*)d_ws + WS_KH);
        f16* kl = (f16*)((char*)d_ws + WS_KL);
        f16* vt = (f16*)((char*)d_ws + WS_VT);
        prep_kv<<<dim3(3072), 256, 0, stream>>>(k, v, kh, kl, vt);
        sdpa_main<<<dim3(1024), 256, 0, stream>>>(q, kh, kl, vt, mask, out, attn);
    } else {
        sdpa_fallback<<<dim3(B_ * (L_ / QT)), 256, 0, stream>>>(q, k, v, mask, out, attn);
    }
}

// Round 12
// 335.730 us; speedup vs baseline: 1.5327x; 1.1772x over previous
//
#include <hip/hip_runtime.h>

#define B_ 64
#define L_ 1024
#define D_ 64
#define QT 16

typedef _Float16 f16;
typedef __attribute__((ext_vector_type(8))) _Float16 f16x8;
typedef __attribute__((ext_vector_type(4))) _Float16 f16x4;
typedef __attribute__((ext_vector_type(4))) float f32x4;
typedef unsigned long long u64;

// workspace layout (bytes): kh 8M | kl 8M | vt 8M | bits 8M = 32 MiB
#define WS_KH 0u
#define WS_KL 8388608u
#define WS_VT 16777216u
#define WS_BT 25165824u
#define WS_NEED 33554432u

#define MFMA16(A, B, C) __builtin_amdgcn_mfma_f32_16x16x32_f16((A), (B), (C), 0, 0, 0)

// ---------------- mega prep: K hi/lo + V transpose + mask->bits ----------------
// blocks [0,2048): K*0.125 -> kh/kl
// blocks [2048,3072): V -> Vt[b][d][k]
// blocks [3072,7168): mask -> bits (1 bit/elem, bits[q*16 + (k>>6)], bit k&63)
__global__ __launch_bounds__(256)
void mega_prep(const float* __restrict__ kk, const float* __restrict__ v,
               const unsigned char* __restrict__ mask,
               f16* __restrict__ kh, f16* __restrict__ kl,
               f16* __restrict__ vt, u64* __restrict__ bits) {
    __shared__ f16 tile[64][72];
    const int bid = blockIdx.x;
    if (bid < 2048) {
        const int i = (bid * 256 + threadIdx.x) * 8;
        float4 f0 = *(const float4*)(kk + i);
        float4 f1 = *(const float4*)(kk + i + 4);
        float fv[8] = {f0.x, f0.y, f0.z, f0.w, f1.x, f1.y, f1.z, f1.w};
        f16x8 h, lo;
        #pragma unroll
        for (int j = 0; j < 8; ++j) {
            float x = fv[j] * 0.125f;
            f16 hh = (f16)x;
            h[j] = hh;
            lo[j] = (f16)(x - (float)hh);
        }
        *(f16x8*)(kh + i) = h;
        *(f16x8*)(kl + i) = lo;
    } else if (bid < 3072) {
        const int bb = bid - 2048;
        const int b = bb >> 4, kt = bb & 15;
        const int r = threadIdx.x >> 2, c0 = (threadIdx.x & 3) * 16;
        const float* vp = v + (size_t)(b * L_ + kt * 64 + r) * D_ + c0;
        float4 g0 = *(const float4*)vp;
        float4 g1 = *(const float4*)(vp + 4);
        float4 g2 = *(const float4*)(vp + 8);
        float4 g3 = *(const float4*)(vp + 12);
        float fv[16] = {g0.x, g0.y, g0.z, g0.w, g1.x, g1.y, g1.z, g1.w,
                        g2.x, g2.y, g2.z, g2.w, g3.x, g3.y, g3.z, g3.w};
        #pragma unroll
        for (int j = 0; j < 16; ++j) tile[r][c0 + j] = (f16)fv[j];
        __syncthreads();
        f16x8 o0, o1;
        #pragma unroll
        for (int j = 0; j < 8; ++j) { o0[j] = tile[c0 + j][r]; o1[j] = tile[c0 + 8 + j][r]; }
        f16* op = vt + (size_t)(b * 64 + r) * 1024 + kt * 64 + c0;
        *(f16x8*)op = o0;
        *(f16x8*)(op + 8) = o1;
    } else {
        // mask -> bits via ballot (fully coalesced cold stream)
        unsigned det = 0;
        {
            const unsigned* mw = (const unsigned*)mask;
            #pragma unroll
            for (int i = 0; i < 32; ++i) det |= mw[i];
        }
        const bool elem4 = (det <= 1u) || (det == 0x3F800000u);
        const int lane = threadIdx.x & 63;
        const size_t total = (size_t)B_ * L_ * L_;
        const size_t stride = (size_t)4096 * 256;
        for (size_t idx = (size_t)(bid - 3072) * 256 + threadIdx.x; idx < total; idx += stride) {
            int val = elem4 ? ((const int*)mask)[idx] : (int)mask[idx];
            u64 bal = __ballot(val != 0);
            if (lane == 0) bits[idx >> 6] = bal;
        }
    }
}

// ---------------- main kernel (R8 structure, bits-based mask) ----------------
// Swapped QK^T: mfma(A=K-frag, B=Q-frag) -> lane owns (q=lr, k=kq+c*16+lg*4+{0..3}).
// Mask: one 32B ulong4 per lane (L3-hot), nibble-extracted per chunk. No cold reads
// in phase A at all -> only L2-hot kh/kl.

__global__ __launch_bounds__(256, 4)
void sdpa_main(const float* __restrict__ q, const f16* __restrict__ kh,
               const f16* __restrict__ kl, const f16* __restrict__ vt,
               const u64* __restrict__ bits,
               float* __restrict__ out, float* __restrict__ attn)
{
    __shared__ __align__(16) char smem[32768];   // staging (4 waves x 8 KB) <-> OL (17.4 KB)
    __shared__ float wsumP[4][QT];
    f16* ST = (f16*)smem;
    float* OL = (float*)smem;

    const int tid = threadIdx.x;
    const int l = tid & 63, w = tid >> 6;
    const int lr = l & 15, lg = l >> 4;
    const int bid0 = blockIdx.x;
    const int bid = (bid0 & 7) * 512 + (bid0 >> 3);   // XCD swizzle (4096 % 8 == 0)
    const int b = bid >> 6, qt = bid & 63;
    const int qbase = b * L_ + qt * QT;
    const int kq = w * 256;
    const int wbase = w * 4096;
    const int swx = (lr & 7) << 3;

    // ---- Q frags hi/lo ----
    f16x8 aqh0, aqh1, aql0, aql1;
    {
        const float* qp = q + (size_t)(qbase + lr) * D_;
        float4 f0 = *(const float4*)(qp + lg * 8);
        float4 f1 = *(const float4*)(qp + lg * 8 + 4);
        float4 f2 = *(const float4*)(qp + 32 + lg * 8);
        float4 f3 = *(const float4*)(qp + 32 + lg * 8 + 4);
        float fa[8] = {f0.x, f0.y, f0.z, f0.w, f1.x, f1.y, f1.z, f1.w};
        float fb[8] = {f2.x, f2.y, f2.z, f2.w, f3.x, f3.y, f3.z, f3.w};
        #pragma unroll
        for (int j = 0; j < 8; ++j) {
            f16 h = (f16)fa[j]; aqh0[j] = h; aql0[j] = (f16)(fa[j] - (float)h);
            h = (f16)fb[j];     aqh1[j] = h; aql1[j] = (f16)(fb[j] - (float)h);
        }
    }

    // ---- mask bits for this lane's quarter: 4 u64 words (32 B, L3-hot) ----
    const u64* bq = bits + (size_t)(qbase + lr) * 16 + w * 4;
    const u64 mw0 = bq[0], mw1 = bq[1], mw2 = bq[2], mw3 = bq[3];

    // ---- phase A: swapped QK^T -> e = bit ? 0 : exp(s) -> staging ----
    const f16* khp = kh + (size_t)(b * L_ + kq + lr) * D_ + lg * 8;
    const f16* klp = kl + (size_t)(b * L_ + kq + lr) * D_ + lg * 8;
    f16x8 kc0 = *(const f16x8*)khp, kc1 = *(const f16x8*)(khp + 32);
    f16x8 lc0 = *(const f16x8*)klp, lc1 = *(const f16x8*)(klp + 32);
    float rsum = 0.f;
    #pragma unroll
    for (int c = 0; c < 16; ++c) {
        f16x8 kn0, kn1, ln0, ln1;
        if (c < 15) {
            const f16* p1 = khp + (c + 1) * 1024;
            const f16* p2 = klp + (c + 1) * 1024;
            kn0 = *(const f16x8*)p1; kn1 = *(const f16x8*)(p1 + 32);
            ln0 = *(const f16x8*)p2; ln1 = *(const f16x8*)(p2 + 32);
        }
        f32x4 aA = {0.f,0.f,0.f,0.f}, aB = {0.f,0.f,0.f,0.f}, aC = {0.f,0.f,0.f,0.f};
        aA = MFMA16(kc0, aqh0, aA); aA = MFMA16(kc1, aqh1, aA);
        aB = MFMA16(kc0, aql0, aB); aB = MFMA16(kc1, aql1, aB);
        aC = MFMA16(lc0, aqh0, aC); aC = MFMA16(lc1, aqh1, aC);
        // bits for k = kq + c*16 + lg*4 + r : word c>>2, nibble (c&3)*16 + lg*4
        const u64 word = (c >> 2) == 0 ? mw0 : (c >> 2) == 1 ? mw1 : (c >> 2) == 2 ? mw2 : mw3;
        const unsigned nib = (unsigned)(word >> ((c & 3) * 16 + lg * 4)) & 0xFu;
        f16x4 qd;
        #pragma unroll
        for (int r = 0; r < 4; ++r) {
            float e = ((nib >> r) & 1u) ? 0.f : __expf(aA[r] + aB[r] + aC[r]);  // |s|<~7
            rsum += e;
            qd[r] = (f16)e;
        }
        *(f16x4*)&ST[(wbase + lr * 256 + c * 16 + lg * 4) ^ swx] = qd;
        if (c < 15) { kc0 = kn0; kc1 = kn1; lc0 = ln0; lc1 = ln1; }
    }

    // ---- wave-local fence, gather PV A-frags ----
    asm volatile("s_waitcnt lgkmcnt(0)" ::: "memory");
    __builtin_amdgcn_sched_barrier(0);
    f16x8 pa[8];
    #pragma unroll
    for (int t = 0; t < 8; ++t)
        pa[t] = *(const f16x8*)&ST[(wbase + lr * 256 + t * 32 + lg * 8) ^ swx];

    rsum += __shfl_xor(rsum, 16);
    rsum += __shfl_xor(rsum, 32);
    if (l < 16) wsumP[w][lr] = rsum;
    __syncthreads();                    // bar1: wsumP ready; staging dead -> OL may reuse

    const float inv = 1.0f / (wsumP[0][lr] + wsumP[1][lr] + wsumP[2][lr] + wsumP[3][lr]);

    // ---- phase C: attn stores (fire-and-forget) interleaved with PV ----
    const f16* vtb = vt + (size_t)b * 64 * 1024 + kq + lg * 8;
    float* ap = attn + (size_t)(qbase + lr) * L_ + kq + lg * 8;
    f32x4 acc4[4] = {{0,0,0,0},{0,0,0,0},{0,0,0,0},{0,0,0,0}};
    f16x8 bc[4];
    #pragma unroll
    for (int nt = 0; nt < 4; ++nt)
        bc[nt] = *(const f16x8*)(vtb + (size_t)(nt * 16 + lr) * 1024);

    #pragma unroll
    for (int t = 0; t < 8; ++t) {
        f16x8 bn[4];
        if (t < 7) {
            #pragma unroll
            for (int nt = 0; nt < 4; ++nt)
                bn[nt] = *(const f16x8*)(vtb + (size_t)(nt * 16 + lr) * 1024 + (t + 1) * 32);
        }
        f32x4 p0, p1;
        p0[0] = (float)pa[t][0] * inv; p0[1] = (float)pa[t][1] * inv;
        p0[2] = (float)pa[t][2] * inv; p0[3] = (float)pa[t][3] * inv;
        p1[0] = (float)pa[t][4] * inv; p1[1] = (float)pa[t][5] * inv;
        p1[2] = (float)pa[t][6] * inv; p1[3] = (float)pa[t][7] * inv;
        *(f32x4*)(ap + t * 32)     = p0;
        *(f32x4*)(ap + t * 32 + 4) = p1;
        #pragma unroll
        for (int nt = 0; nt < 4; ++nt)
            acc4[nt] = MFMA16(pa[t], bc[nt], acc4[nt]);
        if (t < 7) {
            #pragma unroll
            for (int nt = 0; nt < 4; ++nt) bc[nt] = bn[nt];
        }
    }

    // ---- cross-wave O reduction ----
    #pragma unroll
    for (int nt = 0; nt < 4; ++nt) {
        #pragma unroll
        for (int r = 0; r < 4; ++r)
            OL[w * (16 * 68) + (lg * 4 + r) * 68 + nt * 16 + lr] = acc4[nt][r];
    }
    __syncthreads();                    // bar2
    {
        const int row = tid >> 4, c4 = (tid & 15) * 4;
        f32x4 o = {0.f, 0.f, 0.f, 0.f};
        #pragma unroll
        for (int ww = 0; ww < 4; ++ww) {
            const float* p = &OL[ww * (16 * 68) + row * 68 + c4];
            o[0] += p[0]; o[1] += p[1]; o[2] += p[2]; o[3] += p[3];
        }
        const float invr = 1.0f / (wsumP[0][row] + wsumP[1][row] +
                                   wsumP[2][row] + wsumP[3][row]);
        f32x4 r = {o[0] * invr, o[1] * invr, o[2] * invr, o[3] * invr};
        *(f32x4*)(out + (size_t)(qbase + row) * D_ + c4) = r;
    }
}

// ---------------- fallback (round-3 kernel, used if ws too small) ----------------

__device__ __forceinline__ int sidx(int row, int col) {
    return row * 1024 + ((((col >> 3) ^ (row & 7)) << 3) | (col & 7));
}

__global__ __launch_bounds__(256, 4)
void sdpa_fallback(const float* __restrict__ q, const float* __restrict__ kk,
                   const float* __restrict__ v, const unsigned char* __restrict__ mask,
                   float* __restrict__ out, float* __restrict__ attn)
{
    __shared__ f16 S[QT * 1024];
    __shared__ float wmax[4][QT];
    __shared__ float wsum[QT];

    const int tid = threadIdx.x;
    const int l = tid & 63, w = tid >> 6;
    const int lr = l & 15, lg = l >> 4;
    const int bid = blockIdx.x;
    const int b = bid >> 6, qt = bid & 63;
    const int qbase = b * L_ + qt * QT;

    unsigned det = 0;
    {
        const unsigned* mw = (const unsigned*)mask;
        #pragma unroll
        for (int i = 0; i < 32; ++i) det |= mw[i];
    }
    const bool elem4 = (det <= 1u) || (det == 0x3F800000u);

    f16x8 aqh[2], aql[2];
    {
        const float* qp = q + (size_t)(qbase + lr) * D_;
        #pragma unroll
        for (int s = 0; s < 2; ++s) {
            float4 f0 = *(const float4*)(qp + s * 32 + lg * 8);
            float4 f1 = *(const float4*)(qp + s * 32 + lg * 8 + 4);
            float fv[8] = {f0.x, f0.y, f0.z, f0.w, f1.x, f1.y, f1.z, f1.w};
            #pragma unroll
            for (int j = 0; j < 8; ++j) {
                f16 h = (f16)fv[j];
                aqh[s][j] = h;
                aql[s][j] = (f16)(fv[j] - (float)h);
            }
        }
    }

    float vmax[4] = {-INFINITY, -INFINITY, -INFINITY, -INFINITY};
    const float* kb = kk + (size_t)(b * L_ + w * 16 + lr) * D_ + lg * 8;
    const size_t mrowbase = (size_t)(qbase + lg * 4) * L_ + w * 16 + lr;

    float4 kc[4];
    kc[0] = *(const float4*)kb;
    kc[1] = *(const float4*)(kb + 4);
    kc[2] = *(const float4*)(kb + 32);
    kc[3] = *(const float4*)(kb + 36);
    int mcur[4], mnxt[4];
    #pragma unroll
    for (int r2 = 0; r2 < 4; ++r2) {
        if (elem4) {
            mcur[r2] = ((const int*)mask)[mrowbase + (size_t)r2 * L_];
            mnxt[r2] = ((const int*)mask)[mrowbase + (size_t)r2 * L_ + 64];
        } else {
            mcur[r2] = mask[mrowbase + (size_t)r2 * L_];
            mnxt[r2] = mask[mrowbase + (size_t)r2 * L_ + 64];
        }
    }

    for (int ck = 0; ck < 16; ++ck) {
        float4 kn[4];
        if (ck < 15) {
            const float* kp = kb + (size_t)(ck + 1) * 64 * D_;
            kn[0] = *(const float4*)kp;
            kn[1] = *(const float4*)(kp + 4);
            kn[2] = *(const float4*)(kp + 32);
            kn[3] = *(const float4*)(kp + 36);
        }
        int mfut[4];
        if (ck < 14) {
            const size_t mo = mrowbase + (size_t)(ck + 2) * 64;
            if (elem4) {
                #pragma unroll
                for (int r2 = 0; r2 < 4; ++r2) mfut[r2] = ((const int*)mask)[mo + (size_t)r2 * L_];
            } else {
                #pragma unroll
                for (int r2 = 0; r2 < 4; ++r2) mfut[r2] = mask[mo + (size_t)r2 * L_];
            }
        }
        f16x8 bh[2], bl[2];
        #pragma unroll
        for (int s = 0; s < 2; ++s) {
            float fv[8] = {kc[2*s].x, kc[2*s].y, kc[2*s].z, kc[2*s].w,
                           kc[2*s+1].x, kc[2*s+1].y, kc[2*s+1].z, kc[2*s+1].w};
            #pragma unroll
            for (int j = 0; j < 8; ++j) {
                f16 h = (f16)fv[j];
                bh[s][j] = h;
                bl[s][j] = (f16)(fv[j] - (float)h);
            }
        }
        f32x4 acc = {0.f, 0.f, 0.f, 0.f};
        #pragma unroll
        for (int s = 0; s < 2; ++s) {
            acc = MFMA16(aqh[s], bh[s], acc);
            acc = MFMA16(aql[s], bh[s], acc);
            acc = MFMA16(aqh[s], bl[s], acc);
        }
        const int scol = ck * 64 + w * 16 + lr;
        #pragma unroll
        for (int r2 = 0; r2 < 4; ++r2) {
            float sv = mcur[r2] ? -INFINITY : acc[r2] * 0.125f;
            S[sidx(lg * 4 + r2, scol)] = (f16)sv;
            vmax[r2] = fmaxf(vmax[r2], sv);
        }
        #pragma unroll
        for (int r2 = 0; r2 < 4; ++r2) mcur[r2] = mnxt[r2];
        if (ck < 14) {
            #pragma unroll
            for (int r2 = 0; r2 < 4; ++r2) mnxt[r2] = mfut[r2];
        }
        if (ck < 15) {
            #pragma unroll
            for (int j = 0; j < 4; ++j) kc[j] = kn[j];
        }
    }
    #pragma unroll
    for (int r2 = 0; r2 < 4; ++r2) {
        #pragma unroll
        for (int off = 1; off < 16; off <<= 1)
            vmax[r2] = fmaxf(vmax[r2], __shfl_xor(vmax[r2], off));
    }
    if (lr == 0) {
        #pragma unroll
        for (int r2 = 0; r2 < 4; ++r2) wmax[w][lg * 4 + r2] = vmax[r2];
    }
    __syncthreads();

    {
        const int row = tid >> 4, cg = tid & 15;
        const float m = fmaxf(fmaxf(wmax[0][row], wmax[1][row]),
                              fmaxf(wmax[2][row], wmax[3][row]));
        float sum = 0.f;
        #pragma unroll
        for (int c = 0; c < 8; ++c) {
            f16* sp = &S[row * 1024 + (((cg + 16 * c) ^ (row & 7)) << 3)];
            f16x8 sv = *(const f16x8*)sp;
            f16x8 evv;
            #pragma unroll
            for (int j = 0; j < 8; ++j) {
                float e = __expf((float)sv[j] - m);
                evv[j] = (f16)e;
                sum += e;
            }
            *(f16x8*)sp = evv;
        }
        #pragma unroll
        for (int off = 1; off < 16; off <<= 1) sum += __shfl_xor(sum, off);
        if (cg == 0) wsum[row] = sum;
        __syncthreads();

        const float inv = 1.0f / wsum[row];
        float* ap = attn + (size_t)(qbase + row) * L_;
        #pragma unroll
        for (int c = 0; c < 8; ++c) {
            f16x8 evv = *(const f16x8*)&S[row * 1024 + (((cg + 16 * c) ^ (row & 7)) << 3)];
            float4 p0, p1;
            p0.x = (float)evv[0] * inv; p0.y = (float)evv[1] * inv;
            p0.z = (float)evv[2] * inv; p0.w = (float)evv[3] * inv;
            p1.x = (float)evv[4] * inv; p1.y = (float)evv[5] * inv;
            p1.z = (float)evv[6] * inv; p1.w = (float)evv[7] * inv;
            *(float4*)(ap + (cg + 16 * c) * 8)     = p0;
            *(float4*)(ap + (cg + 16 * c) * 8 + 4) = p1;
        }
    }

    f32x4 acc2 = {0.f, 0.f, 0.f, 0.f};
    const float* vb = v + (size_t)(b * L_) * D_ + w * 16 + lr;
    float vcA[8], vcB[8];
    #pragma unroll
    for (int j = 0; j < 8; ++j) {
        vcA[j] = vb[(size_t)(lg * 8 + j) * D_];
        vcB[j] = vb[(size_t)(32 + lg * 8 + j) * D_];
    }
    for (int tt = 0; tt < 16; ++tt) {
        {
            f16x8 pa = *(const f16x8*)&S[lr * 1024 + ((((2 * tt) * 4 + lg) ^ (lr & 7)) << 3)];
            f16x8 bv;
            #pragma unroll
            for (int j = 0; j < 8; ++j) bv[j] = (f16)vcA[j];
            if (tt < 15) {
                const float* vp = vb + (size_t)((2 * tt + 2) * 32 + lg * 8) * D_;
                #pragma unroll
                for (int j = 0; j < 8; ++j) vcA[j] = vp[(size_t)j * D_];
            }
            acc2 = MFMA16(pa, bv, acc2);
        }
        {
            f16x8 pa = *(const f16x8*)&S[lr * 1024 + ((((2 * tt + 1) * 4 + lg) ^ (lr & 7)) << 3)];
            f16x8 bv;
            #pragma unroll
            for (int j = 0; j < 8; ++j) bv[j] = (f16)vcB[j];
            if (tt < 15) {
                const float* vp = vb + (size_t)((2 * tt + 3) * 32 + lg * 8) * D_;
                #pragma unroll
                for (int j = 0; j < 8; ++j) vcB[j] = vp[(size_t)j * D_];
            }
            acc2 = MFMA16(pa, bv, acc2);
        }
    }

    #pragma unroll
    for (int r2 = 0; r2 < 4; ++r2) {
        const float invr = 1.0f / wsum[lg * 4 + r2];
        out[(size_t)(qbase + lg * 4 + r2) * D_ + w * 16 + lr] = acc2[r2] * invr;
    }
}

extern "C" void kernel_launch(void* const* d_in, const int* in_sizes, int n_in,
                              void* d_out, int out_size, void* d_ws, size_t ws_size,
                              hipStream_t stream) {
    const float* q = (const float*)d_in[0];
    const float* k = (const float*)d_in[1];
    const float* v = (const float*)d_in[2];
    const unsigned char* mask = (const unsigned char*)d_in[3];
    float* out = (float*)d_out;
    float* attn = out + (size_t)B_ * L_ * D_;

    if (ws_size >= (size_t)WS_NEED) {
        f16* kh = (f16*)((char*)d_ws + WS_KH);
        f16* kl = (f16*)((char*)d_ws + WS_KL);
        f16* vt = (f16*)((char*)d_ws + WS_VT);
        u64* bits = (u64*)((char*)d_ws + WS_BT);
        mega_prep<<<dim3(7168), 256, 0, stream>>>(k, v, mask, kh, kl, vt, bits);
        sdpa_main<<<dim3(B_ * (L_ / QT)), 256, 0, stream>>>(q, kh, kl, vt, bits, out, attn);
    } else {
        sdpa_fallback<<<dim3(B_ * (L_ / QT)), 256, 0, stream>>>(q, k, v, mask, out, attn);
    }
}

// Round 13
// 328.940 us; speedup vs baseline: 1.5644x; 1.0206x over previous
//
#include <hip/hip_runtime.h>

#define B_ 64
#define L_ 1024
#define D_ 64
#define QT 16

typedef _Float16 f16;
typedef __attribute__((ext_vector_type(8))) _Float16 f16x8;
typedef __attribute__((ext_vector_type(4))) _Float16 f16x4;
typedef __attribute__((ext_vector_type(4))) float f32x4;
typedef unsigned long long u64;
typedef unsigned long long u64x4 __attribute__((ext_vector_type(4)));

// workspace layout (bytes): kh 8M | vt 8M | bits 8M = 24 MiB
#define WS_KH 0u
#define WS_VT 8388608u
#define WS_BT 16777216u
#define WS_NEED 25165824u

#define MFMA32(A, B, C) __builtin_amdgcn_mfma_f32_16x16x32_f16((A), (B), (C), 0, 0, 0)
#define PV16(A, B, C)   __builtin_amdgcn_mfma_f32_16x16x16f16((A), (B), (C), 0, 0, 0)

// ---------------- mega prep ----------------
// blocks [0,2048): K*0.125 -> kh (f16)
// blocks [2048,3072): V -> Vt[b][d][k] (f16)
// blocks [3072,5120): mask -> bits, interleaved layout: per 256-elem span s,
//   4 u64 words b0..b3 at bits[s*4]; bit i of b_j = elem 4i+j of the span.
__global__ __launch_bounds__(256)
void mega_prep(const float* __restrict__ kk, const float* __restrict__ v,
               const unsigned char* __restrict__ mask,
               f16* __restrict__ kh, f16* __restrict__ vt, u64* __restrict__ bits) {
    __shared__ f16 tile[64][72];
    const int bid = blockIdx.x;
    if (bid < 2048) {
        const int i = (bid * 256 + threadIdx.x) * 8;
        float4 f0 = *(const float4*)(kk + i);
        float4 f1 = *(const float4*)(kk + i + 4);
        float fv[8] = {f0.x, f0.y, f0.z, f0.w, f1.x, f1.y, f1.z, f1.w};
        f16x8 h;
        #pragma unroll
        for (int j = 0; j < 8; ++j) h[j] = (f16)(fv[j] * 0.125f);
        *(f16x8*)(kh + i) = h;
    } else if (bid < 3072) {
        const int bb = bid - 2048;
        const int b = bb >> 4, kt = bb & 15;
        const int r = threadIdx.x >> 2, c0 = (threadIdx.x & 3) * 16;
        const float* vp = v + (size_t)(b * L_ + kt * 64 + r) * D_ + c0;
        float4 g0 = *(const float4*)vp;
        float4 g1 = *(const float4*)(vp + 4);
        float4 g2 = *(const float4*)(vp + 8);
        float4 g3 = *(const float4*)(vp + 12);
        float fv[16] = {g0.x, g0.y, g0.z, g0.w, g1.x, g1.y, g1.z, g1.w,
                        g2.x, g2.y, g2.z, g2.w, g3.x, g3.y, g3.z, g3.w};
        #pragma unroll
        for (int j = 0; j < 16; ++j) tile[r][c0 + j] = (f16)fv[j];
        __syncthreads();
        f16x8 o0, o1;
        #pragma unroll
        for (int j = 0; j < 8; ++j) { o0[j] = tile[c0 + j][r]; o1[j] = tile[c0 + 8 + j][r]; }
        f16* op = vt + (size_t)(b * 64 + r) * 1024 + kt * 64 + c0;
        *(f16x8*)op = o0;
        *(f16x8*)(op + 8) = o1;
    } else {
        unsigned det = 0;
        {
            const unsigned* mw = (const unsigned*)mask;
            #pragma unroll
            for (int i = 0; i < 32; ++i) det |= mw[i];
        }
        const bool elem4 = (det <= 1u) || (det == 0x3F800000u);
        const int lane = threadIdx.x & 63;
        const int gw = (bid - 3072) * 4 + (threadIdx.x >> 6);
        for (int s = gw; s < 262144; s += 8192) {       // 64M elems / 256 per span
            unsigned nib;
            if (elem4) {
                const int4 m = *(const int4*)((const int*)mask + (size_t)s * 256 + lane * 4);
                nib = (m.x != 0 ? 1u : 0u) | (m.y != 0 ? 2u : 0u) |
                      (m.z != 0 ? 4u : 0u) | (m.w != 0 ? 8u : 0u);
            } else {
                const uchar4 m = *(const uchar4*)(mask + (size_t)s * 256 + lane * 4);
                nib = (m.x ? 1u : 0u) | (m.y ? 2u : 0u) | (m.z ? 4u : 0u) | (m.w ? 8u : 0u);
            }
            u64 b0 = __ballot((nib & 1u) != 0u);
            u64 b1 = __ballot((nib & 2u) != 0u);
            u64 b2 = __ballot((nib & 4u) != 0u);
            u64 b3 = __ballot((nib & 8u) != 0u);
            if (lane == 0) {
                u64x4 o = {b0, b1, b2, b3};
                *(u64x4*)(bits + (size_t)s * 4) = o;
            }
        }
    }
}

// ---------------- main: one wave = one 16-q tile; no barriers, no LDS ----------------
// Pass 1: swapped QK^T (A=K-frag, B=Q-frag) -> masked rowsum (nothing stored).
// Pass 2: recompute QK^T -> p = e*inv -> attn store (f32x4) + PV via 16x16x16 MFMA,
//   whose A-fragment layout is identical to the QK^T accumulator layout (lane-local chain).

__global__ __launch_bounds__(256, 4)
void sdpa_main(const float* __restrict__ q, const f16* __restrict__ kh,
               const f16* __restrict__ vt, const u64* __restrict__ bits,
               float* __restrict__ out, float* __restrict__ attn)
{
    const int tid = threadIdx.x;
    const int l = tid & 63, w = tid >> 6;
    const int lr = l & 15, lg = l >> 4;
    const int bid0 = blockIdx.x;
    const int bid = (bid0 & 7) * 128 + (bid0 >> 3);   // XCD swizzle (1024 % 8 == 0)
    const int tile_id = bid * 4 + w;                  // wave-private q-tile
    const int b = tile_id >> 6;
    const int qbase = tile_id * QT;                   // global q-row base

    // ---- Q frag (single f16; kh carries the 1/8 scale) ----
    f16x8 aq0, aq1;
    {
        const float* qp = q + (size_t)(qbase + lr) * D_;
        float4 f0 = *(const float4*)(qp + lg * 8);
        float4 f1 = *(const float4*)(qp + lg * 8 + 4);
        float4 f2 = *(const float4*)(qp + 32 + lg * 8);
        float4 f3 = *(const float4*)(qp + 32 + lg * 8 + 4);
        aq0[0] = (f16)f0.x; aq0[1] = (f16)f0.y; aq0[2] = (f16)f0.z; aq0[3] = (f16)f0.w;
        aq0[4] = (f16)f1.x; aq0[5] = (f16)f1.y; aq0[6] = (f16)f1.z; aq0[7] = (f16)f1.w;
        aq1[0] = (f16)f2.x; aq1[1] = (f16)f2.y; aq1[2] = (f16)f2.z; aq1[3] = (f16)f2.w;
        aq1[4] = (f16)f3.x; aq1[5] = (f16)f3.y; aq1[6] = (f16)f3.z; aq1[7] = (f16)f3.w;
    }

    const f16* khb = kh + (size_t)b * (L_ * D_) + lg * 8;
    const f16* vtb = vt + (size_t)b * (D_ * L_);
    const u64x4* bp = (const u64x4*)bits + (size_t)(qbase + lr) * 4;

    // ---------- pass 1: masked rowsum ----------
    float rsum = 0.f;
    f16x8 kc0, kc1;
    {
        const f16* kp = khb + (size_t)lr * D_;
        kc0 = *(const f16x8*)kp;
        kc1 = *(const f16x8*)(kp + 32);
    }
    #pragma unroll
    for (int sp = 0; sp < 4; ++sp) {
        const u64x4 bw = bp[sp];
        #pragma unroll 4
        for (int cc = 0; cc < 16; ++cc) {
            const int c = sp * 16 + cc;
            f16x8 kn0, kn1;
            if (c < 63) {
                const f16* kp = khb + (size_t)((c + 1) * 16 + lr) * D_;
                kn0 = *(const f16x8*)kp;
                kn1 = *(const f16x8*)(kp + 32);
            }
            f32x4 s = {0.f, 0.f, 0.f, 0.f};
            s = MFMA32(kc0, aq0, s);
            s = MFMA32(kc1, aq1, s);
            const int sh = cc * 4 + lg;
            rsum += ((unsigned)(bw[0] >> sh) & 1u) ? 0.f : __expf(s[0]);
            rsum += ((unsigned)(bw[1] >> sh) & 1u) ? 0.f : __expf(s[1]);
            rsum += ((unsigned)(bw[2] >> sh) & 1u) ? 0.f : __expf(s[2]);
            rsum += ((unsigned)(bw[3] >> sh) & 1u) ? 0.f : __expf(s[3]);
            kc0 = kn0; kc1 = kn1;
        }
    }
    rsum += __shfl_xor(rsum, 16);
    rsum += __shfl_xor(rsum, 32);
    const float inv = 1.0f / rsum;

    // ---------- pass 2: attn + PV (recompute; operands L2-warm) ----------
    f32x4 o0 = {0.f,0.f,0.f,0.f}, o1 = {0.f,0.f,0.f,0.f};
    f32x4 o2 = {0.f,0.f,0.f,0.f}, o3 = {0.f,0.f,0.f,0.f};
    {
        const f16* kp = khb + (size_t)lr * D_;
        kc0 = *(const f16x8*)kp;
        kc1 = *(const f16x8*)(kp + 32);
    }
    float* ap = attn + (size_t)(qbase + lr) * L_ + lg * 4;
    const f16* vpb = vtb + (size_t)lr * L_ + lg * 4;
    #pragma unroll
    for (int sp = 0; sp < 4; ++sp) {
        const u64x4 bw = bp[sp];
        #pragma unroll 4
        for (int cc = 0; cc < 16; ++cc) {
            const int c = sp * 16 + cc;
            f16x8 kn0, kn1;
            if (c < 63) {
                const f16* kp = khb + (size_t)((c + 1) * 16 + lr) * D_;
                kn0 = *(const f16x8*)kp;
                kn1 = *(const f16x8*)(kp + 32);
            }
            f32x4 s = {0.f, 0.f, 0.f, 0.f};
            s = MFMA32(kc0, aq0, s);
            s = MFMA32(kc1, aq1, s);
            const int sh = cc * 4 + lg;
            f32x4 p;
            p[0] = (((unsigned)(bw[0] >> sh) & 1u) ? 0.f : __expf(s[0])) * inv;
            p[1] = (((unsigned)(bw[1] >> sh) & 1u) ? 0.f : __expf(s[1])) * inv;
            p[2] = (((unsigned)(bw[2] >> sh) & 1u) ? 0.f : __expf(s[2])) * inv;
            p[3] = (((unsigned)(bw[3] >> sh) & 1u) ? 0.f : __expf(s[3])) * inv;
            *(f32x4*)(ap + c * 16) = p;                 // attn (fire-and-forget, spread)
            f16x4 pa;
            pa[0] = (f16)p[0]; pa[1] = (f16)p[1]; pa[2] = (f16)p[2]; pa[3] = (f16)p[3];
            const f16* vp = vpb + c * 16;
            f16x4 v0 = *(const f16x4*)vp;
            f16x4 v1 = *(const f16x4*)(vp + 16 * L_);
            f16x4 v2 = *(const f16x4*)(vp + 32 * L_);
            f16x4 v3 = *(const f16x4*)(vp + 48 * L_);
            o0 = PV16(pa, v0, o0);
            o1 = PV16(pa, v1, o1);
            o2 = PV16(pa, v2, o2);
            o3 = PV16(pa, v3, o3);
            kc0 = kn0; kc1 = kn1;
        }
    }

    // ---------- out: lane holds O[q=lg*4+r][d=nt*16+lr] (already normalized) ----------
    float* op = out + (size_t)(qbase + lg * 4) * D_ + lr;
    #pragma unroll
    for (int r = 0; r < 4; ++r) {
        op[r * D_ + 0]  = o0[r];
        op[r * D_ + 16] = o1[r];
        op[r * D_ + 32] = o2[r];
        op[r * D_ + 48] = o3[r];
    }
}

// ---------------- fallback (round-3 kernel, used if ws too small) ----------------

__device__ __forceinline__ int sidx(int row, int col) {
    return row * 1024 + ((((col >> 3) ^ (row & 7)) << 3) | (col & 7));
}

__global__ __launch_bounds__(256, 4)
void sdpa_fallback(const float* __restrict__ q, const float* __restrict__ kk,
                   const float* __restrict__ v, const unsigned char* __restrict__ mask,
                   float* __restrict__ out, float* __restrict__ attn)
{
    __shared__ f16 S[QT * 1024];
    __shared__ float wmax[4][QT];
    __shared__ float wsum[QT];

    const int tid = threadIdx.x;
    const int l = tid & 63, w = tid >> 6;
    const int lr = l & 15, lg = l >> 4;
    const int bid = blockIdx.x;
    const int b = bid >> 6, qt = bid & 63;
    const int qbase = b * L_ + qt * QT;

    unsigned det = 0;
    {
        const unsigned* mw = (const unsigned*)mask;
        #pragma unroll
        for (int i = 0; i < 32; ++i) det |= mw[i];
    }
    const bool elem4 = (det <= 1u) || (det == 0x3F800000u);

    f16x8 aqh[2], aql[2];
    {
        const float* qp = q + (size_t)(qbase + lr) * D_;
        #pragma unroll
        for (int s = 0; s < 2; ++s) {
            float4 f0 = *(const float4*)(qp + s * 32 + lg * 8);
            float4 f1 = *(const float4*)(qp + s * 32 + lg * 8 + 4);
            float fv[8] = {f0.x, f0.y, f0.z, f0.w, f1.x, f1.y, f1.z, f1.w};
            #pragma unroll
            for (int j = 0; j < 8; ++j) {
                f16 h = (f16)fv[j];
                aqh[s][j] = h;
                aql[s][j] = (f16)(fv[j] - (float)h);
            }
        }
    }

    float vmax[4] = {-INFINITY, -INFINITY, -INFINITY, -INFINITY};
    const float* kb = kk + (size_t)(b * L_ + w * 16 + lr) * D_ + lg * 8;
    const size_t mrowbase = (size_t)(qbase + lg * 4) * L_ + w * 16 + lr;

    float4 kc[4];
    kc[0] = *(const float4*)kb;
    kc[1] = *(const float4*)(kb + 4);
    kc[2] = *(const float4*)(kb + 32);
    kc[3] = *(const float4*)(kb + 36);
    int mcur[4], mnxt[4];
    #pragma unroll
    for (int r2 = 0; r2 < 4; ++r2) {
        if (elem4) {
            mcur[r2] = ((const int*)mask)[mrowbase + (size_t)r2 * L_];
            mnxt[r2] = ((const int*)mask)[mrowbase + (size_t)r2 * L_ + 64];
        } else {
            mcur[r2] = mask[mrowbase + (size_t)r2 * L_];
            mnxt[r2] = mask[mrowbase + (size_t)r2 * L_ + 64];
        }
    }

    for (int ck = 0; ck < 16; ++ck) {
        float4 kn[4];
        if (ck < 15) {
            const float* kp = kb + (size_t)(ck + 1) * 64 * D_;
            kn[0] = *(const float4*)kp;
            kn[1] = *(const float4*)(kp + 4);
            kn[2] = *(const float4*)(kp + 32);
            kn[3] = *(const float4*)(kp + 36);
        }
        int mfut[4];
        if (ck < 14) {
            const size_t mo = mrowbase + (size_t)(ck + 2) * 64;
            if (elem4) {
                #pragma unroll
                for (int r2 = 0; r2 < 4; ++r2) mfut[r2] = ((const int*)mask)[mo + (size_t)r2 * L_];
            } else {
                #pragma unroll
                for (int r2 = 0; r2 < 4; ++r2) mfut[r2] = mask[mo + (size_t)r2 * L_];
            }
        }
        f16x8 bh[2], bl[2];
        #pragma unroll
        for (int s = 0; s < 2; ++s) {
            float fv[8] = {kc[2*s].x, kc[2*s].y, kc[2*s].z, kc[2*s].w,
                           kc[2*s+1].x, kc[2*s+1].y, kc[2*s+1].z, kc[2*s+1].w};
            #pragma unroll
            for (int j = 0; j < 8; ++j) {
                f16 h = (f16)fv[j];
                bh[s][j] = h;
                bl[s][j] = (f16)(fv[j] - (float)h);
            }
        }
        f32x4 acc = {0.f, 0.f, 0.f, 0.f};
        #pragma unroll
        for (int s = 0; s < 2; ++s) {
            acc = MFMA32(aqh[s], bh[s], acc);
            acc = MFMA32(aql[s], bh[s], acc);
            acc = MFMA32(aqh[s], bl[s], acc);
        }
        const int scol = ck * 64 + w * 16 + lr;
        #pragma unroll
        for (int r2 = 0; r2 < 4; ++r2) {
            float sv = mcur[r2] ? -INFINITY : acc[r2] * 0.125f;
            S[sidx(lg * 4 + r2, scol)] = (f16)sv;
            vmax[r2] = fmaxf(vmax[r2], sv);
        }
        #pragma unroll
        for (int r2 = 0; r2 < 4; ++r2) mcur[r2] = mnxt[r2];
        if (ck < 14) {
            #pragma unroll
            for (int r2 = 0; r2 < 4; ++r2) mnxt[r2] = mfut[r2];
        }
        if (ck < 15) {
            #pragma unroll
            for (int j = 0; j < 4; ++j) kc[j] = kn[j];
        }
    }
    #pragma unroll
    for (int r2 = 0; r2 < 4; ++r2) {
        #pragma unroll
        for (int off = 1; off < 16; off <<= 1)
            vmax[r2] = fmaxf(vmax[r2], __shfl_xor(vmax[r2], off));
    }
    if (lr == 0) {
        #pragma unroll
        for (int r2 = 0; r2 < 4; ++r2) wmax[w][lg * 4 + r2] = vmax[r2];
    }
    __syncthreads();

    {
        const int row = tid >> 4, cg = tid & 15;
        const float m = fmaxf(fmaxf(wmax[0][row], wmax[1][row]),
                              fmaxf(wmax[2][row], wmax[3][row]));
        float sum = 0.f;
        #pragma unroll
        for (int c = 0; c < 8; ++c) {
            f16* sp = &S[row * 1024 + (((cg + 16 * c) ^ (row & 7)) << 3)];
            f16x8 sv = *(const f16x8*)sp;
            f16x8 evv;
            #pragma unroll
            for (int j = 0; j < 8; ++j) {
                float e = __expf((float)sv[j] - m);
                evv[j] = (f16)e;
                sum += e;
            }
            *(f16x8*)sp = evv;
        }
        #pragma unroll
        for (int off = 1; off < 16; off <<= 1) sum += __shfl_xor(sum, off);
        if (cg == 0) wsum[row] = sum;
        __syncthreads();

        const float inv = 1.0f / wsum[row];
        float* ap = attn + (size_t)(qbase + row) * L_;
        #pragma unroll
        for (int c = 0; c < 8; ++c) {
            f16x8 evv = *(const f16x8*)&S[row * 1024 + (((cg + 16 * c) ^ (row & 7)) << 3)];
            float4 p0, p1;
            p0.x = (float)evv[0] * inv; p0.y = (float)evv[1] * inv;
            p0.z = (float)evv[2] * inv; p0.w = (float)evv[3] * inv;
            p1.x = (float)evv[4] * inv; p1.y = (float)evv[5] * inv;
            p1.z = (float)evv[6] * inv; p1.w = (float)evv[7] * inv;
            *(float4*)(ap + (cg + 16 * c) * 8)     = p0;
            *(float4*)(ap + (cg + 16 * c) * 8 + 4) = p1;
        }
    }

    f32x4 acc2 = {0.f, 0.f, 0.f, 0.f};
    const float* vb = v + (size_t)(b * L_) * D_ + w * 16 + lr;
    float vcA[8], vcB[8];
    #pragma unroll
    for (int j = 0; j < 8; ++j) {
        vcA[j] = vb[(size_t)(lg * 8 + j) * D_];
        vcB[j] = vb[(size_t)(32 + lg * 8 + j) * D_];
    }
    for (int tt = 0; tt < 16; ++tt) {
        {
            f16x8 pa = *(const f16x8*)&S[lr * 1024 + ((((2 * tt) * 4 + lg) ^ (lr & 7)) << 3)];
            f16x8 bv;
            #pragma unroll
            for (int j = 0; j < 8; ++j) bv[j] = (f16)vcA[j];
            if (tt < 15) {
                const float* vp = vb + (size_t)((2 * tt + 2) * 32 + lg * 8) * D_;
                #pragma unroll
                for (int j = 0; j < 8; ++j) vcA[j] = vp[(size_t)j * D_];
            }
            acc2 = MFMA32(pa, bv, acc2);
        }
        {
            f16x8 pa = *(const f16x8*)&S[lr * 1024 + ((((2 * tt + 1) * 4 + lg) ^ (lr & 7)) << 3)];
            f16x8 bv;
            #pragma unroll
            for (int j = 0; j < 8; ++j) bv[j] = (f16)vcB[j];
            if (tt < 15) {
                const float* vp = vb + (size_t)((2 * tt + 3) * 32 + lg * 8) * D_;
                #pragma unroll
                for (int j = 0; j < 8; ++j) vcB[j] = vp[(size_t)j * D_];
            }
            acc2 = MFMA32(pa, bv, acc2);
        }
    }

    #pragma unroll
    for (int r2 = 0; r2 < 4; ++r2) {
        const float invr = 1.0f / wsum[lg * 4 + r2];
        out[(size_t)(qbase + lg * 4 + r2) * D_ + w * 16 + lr] = acc2[r2] * invr;
    }
}

extern "C" void kernel_launch(void* const* d_in, const int* in_sizes, int n_in,
                              void* d_out, int out_size, void* d_ws, size_t ws_size,
                              hipStream_t stream) {
    const float* q = (const float*)d_in[0];
    const float* k = (const float*)d_in[1];
    const float* v = (const float*)d_in[2];
    const unsigned char* mask = (const unsigned char*)d_in[3];
    float* out = (float*)d_out;
    float* attn = out + (size_t)B_ * L_ * D_;

    if (ws_size >= (size_t)WS_NEED) {
        f16* kh = (f16*)((char*)d_ws + WS_KH);
        f16* vt = (f16*)((char*)d_ws + WS_VT);
        u64* bits = (u64*)((char*)d_ws + WS_BT);
        mega_prep<<<dim3(5120), 256, 0, stream>>>(k, v, mask, kh, vt, bits);
        sdpa_main<<<dim3(1024), 256, 0, stream>>>(q, kh, vt, bits, out, attn);
    } else {
        sdpa_fallback<<<dim3(B_ * (L_ / QT)), 256, 0, stream>>>(q, k, v, mask, out, attn);
    }
}

// Round 14
// 300.655 us; speedup vs baseline: 1.7115x; 1.0941x over previous
//
#include <hip/hip_runtime.h>

#define B_ 64
#define L_ 1024
#define D_ 64
#define QT 16

typedef _Float16 f16;
typedef __attribute__((ext_vector_type(8))) _Float16 f16x8;
typedef __attribute__((ext_vector_type(4))) _Float16 f16x4;
typedef __attribute__((ext_vector_type(4))) float f32x4;
typedef unsigned long long u64;
typedef unsigned long long u64x4 __attribute__((ext_vector_type(4)));

// workspace: kpack 8M | vpack 8M | bits 8M = 24 MiB
#define WS_KP 0u
#define WS_VP 8388608u
#define WS_BT 16777216u
#define WS_NEED 25165824u

#define MFMA32(A, B, C) __builtin_amdgcn_mfma_f32_16x16x32_f16((A), (B), (C), 0, 0, 0)
#define PV16(A, B, C)   __builtin_amdgcn_mfma_f32_16x16x16f16((A), (B), (C), 0, 0, 0)

// ---------------- mega prep ----------------
// blocks [0,2048): K*0.125 -> kpack in MFMA A-frag order:
//   kpack[b*65536 + (c*2+h)*512 + l*8 + j] = K[b][c*16+(l&15)][h*32+(l>>4)*8+j]*0.125
// blocks [2048,3072): V -> vpack in PV16 B-frag order:
//   vpack[b*65536 + c*1024 + nt*256 + l*4 + j] = V[b][c*16+(l>>4)*4+j][nt*16+(l&15)]
// blocks [3072,5120): mask -> bits (4-way interleaved ballot words per 256-span)
__global__ __launch_bounds__(256)
void mega_prep(const float* __restrict__ kk, const float* __restrict__ v,
               const unsigned char* __restrict__ mask,
               f16* __restrict__ kpack, f16* __restrict__ vpack, u64* __restrict__ bits) {
    __shared__ f16 tile[64][72];
    const int bid = blockIdx.x;
    const int l = threadIdx.x & 63;
    const int lr = l & 15, lg = l >> 4;
    if (bid < 2048) {
        const int gw = bid * 4 + (threadIdx.x >> 6);   // 0..8191 = (b, c, h)
        const int b = gw >> 7, wid = gw & 127;
        const int c = wid >> 1, h = wid & 1;
        const float* kp = kk + ((size_t)(b * L_ + c * 16 + lr)) * D_ + h * 32 + lg * 8;
        float4 f0 = *(const float4*)kp;
        float4 f1 = *(const float4*)(kp + 4);
        f16x8 o;
        o[0] = (f16)(f0.x * 0.125f); o[1] = (f16)(f0.y * 0.125f);
        o[2] = (f16)(f0.z * 0.125f); o[3] = (f16)(f0.w * 0.125f);
        o[4] = (f16)(f1.x * 0.125f); o[5] = (f16)(f1.y * 0.125f);
        o[6] = (f16)(f1.z * 0.125f); o[7] = (f16)(f1.w * 0.125f);
        *(f16x8*)(kpack + (size_t)gw * 512 + l * 8) = o;
    } else if (bid < 3072) {
        const int bb = bid - 2048;
        const int b = bb >> 4, kt = bb & 15;
        const int r = threadIdx.x >> 2, c0 = (threadIdx.x & 3) * 16;
        const float* vp = v + (size_t)(b * L_ + kt * 64 + r) * D_ + c0;
        float4 g0 = *(const float4*)vp;
        float4 g1 = *(const float4*)(vp + 4);
        float4 g2 = *(const float4*)(vp + 8);
        float4 g3 = *(const float4*)(vp + 12);
        float fv[16] = {g0.x, g0.y, g0.z, g0.w, g1.x, g1.y, g1.z, g1.w,
                        g2.x, g2.y, g2.z, g2.w, g3.x, g3.y, g3.z, g3.w};
        #pragma unroll
        for (int j = 0; j < 16; ++j) tile[r][c0 + j] = (f16)fv[j];
        __syncthreads();
        const int cl = threadIdx.x >> 6;               // c_local 0..3
        const int c = kt * 4 + cl;
        #pragma unroll
        for (int nt = 0; nt < 4; ++nt) {
            f16x4 o;
            #pragma unroll
            for (int j = 0; j < 4; ++j)
                o[j] = tile[cl * 16 + lg * 4 + j][nt * 16 + lr];
            *(f16x4*)(vpack + (size_t)b * 65536 + c * 1024 + nt * 256 + l * 4) = o;
        }
    } else {
        unsigned det = 0;
        {
            const unsigned* mw = (const unsigned*)mask;
            #pragma unroll
            for (int i = 0; i < 32; ++i) det |= mw[i];
        }
        const bool elem4 = (det <= 1u) || (det == 0x3F800000u);
        const int gw = (bid - 3072) * 4 + (threadIdx.x >> 6);
        for (int s = gw; s < 262144; s += 8192) {
            unsigned nib;
            if (elem4) {
                const int4 m = *(const int4*)((const int*)mask + (size_t)s * 256 + l * 4);
                nib = (m.x != 0 ? 1u : 0u) | (m.y != 0 ? 2u : 0u) |
                      (m.z != 0 ? 4u : 0u) | (m.w != 0 ? 8u : 0u);
            } else {
                const uchar4 m = *(const uchar4*)(mask + (size_t)s * 256 + l * 4);
                nib = (m.x ? 1u : 0u) | (m.y ? 2u : 0u) | (m.z ? 4u : 0u) | (m.w ? 8u : 0u);
            }
            u64 b0 = __ballot((nib & 1u) != 0u);
            u64 b1 = __ballot((nib & 2u) != 0u);
            u64 b2 = __ballot((nib & 4u) != 0u);
            u64 b3 = __ballot((nib & 8u) != 0u);
            if (l == 0) {
                u64x4 o = {b0, b1, b2, b3};
                *(u64x4*)(bits + (size_t)s * 4) = o;
            }
        }
    }
}

// ---------------- main: one wave = one 16-q tile; coalesced-only hot loop ----------------
// Pass 1: swapped QK^T (A=kpack frag) -> masked rowsum. Pass 2: recompute -> p -> LDS
// span tile (wave-private, XOR-swizzled) -> coalesced 1KB attn flush; p chains into PV16.

__global__ __launch_bounds__(256, 3)
void sdpa_main(const float* __restrict__ q, const f16* __restrict__ kpack,
               const f16* __restrict__ vpack, const u64* __restrict__ bits,
               float* __restrict__ out, float* __restrict__ attn)
{
    __shared__ f16 SL[4 * 4096];                      // 8 KB per wave: 16q x 256k f16
    const int tid = threadIdx.x;
    const int l = tid & 63, w = tid >> 6;
    const int lr = l & 15, lg = l >> 4;
    const int bid0 = blockIdx.x;
    const int bid = (bid0 & 7) * 128 + (bid0 >> 3);   // XCD swizzle (1024 % 8 == 0)
    const int tile_id = bid * 4 + w;
    const int b = tile_id >> 6;
    const int qbase = tile_id * QT;

    // Q frag (single f16; kpack carries the 1/8 scale)
    f16x8 aq0, aq1;
    {
        const float* qp = q + (size_t)(qbase + lr) * D_;
        float4 f0 = *(const float4*)(qp + lg * 8);
        float4 f1 = *(const float4*)(qp + lg * 8 + 4);
        float4 f2 = *(const float4*)(qp + 32 + lg * 8);
        float4 f3 = *(const float4*)(qp + 32 + lg * 8 + 4);
        aq0[0] = (f16)f0.x; aq0[1] = (f16)f0.y; aq0[2] = (f16)f0.z; aq0[3] = (f16)f0.w;
        aq0[4] = (f16)f1.x; aq0[5] = (f16)f1.y; aq0[6] = (f16)f1.z; aq0[7] = (f16)f1.w;
        aq1[0] = (f16)f2.x; aq1[1] = (f16)f2.y; aq1[2] = (f16)f2.z; aq1[3] = (f16)f2.w;
        aq1[4] = (f16)f3.x; aq1[5] = (f16)f3.y; aq1[6] = (f16)f3.z; aq1[7] = (f16)f3.w;
    }

    const f16* kpb = kpack + (size_t)b * 65536;       // + c*1024 + h*512 + l*8
    const f16* vpb = vpack + (size_t)b * 65536;       // + c*1024 + nt*256 + l*4
    const u64x4* bp = (const u64x4*)bits + (size_t)(qbase + lr) * 4;

    // ---------- pass 1: masked rowsum (coalesced kpack loads only) ----------
    float rsum = 0.f;
    f16x8 kc0 = *(const f16x8*)(kpb + l * 8);
    f16x8 kc1 = *(const f16x8*)(kpb + 512 + l * 8);
    #pragma unroll
    for (int sp = 0; sp < 4; ++sp) {
        const u64x4 bw = bp[sp];
        #pragma unroll
        for (int cc = 0; cc < 16; ++cc) {
            const int c = sp * 16 + cc;
            f16x8 kn0, kn1;
            if (c < 63) {
                kn0 = *(const f16x8*)(kpb + (c + 1) * 1024 + l * 8);
                kn1 = *(const f16x8*)(kpb + (c + 1) * 1024 + 512 + l * 8);
            }
            f32x4 s = {0.f, 0.f, 0.f, 0.f};
            s = MFMA32(kc0, aq0, s);
            s = MFMA32(kc1, aq1, s);
            const int sh = cc * 4 + lg;
            rsum += ((unsigned)(bw[0] >> sh) & 1u) ? 0.f : __expf(s[0]);
            rsum += ((unsigned)(bw[1] >> sh) & 1u) ? 0.f : __expf(s[1]);
            rsum += ((unsigned)(bw[2] >> sh) & 1u) ? 0.f : __expf(s[2]);
            rsum += ((unsigned)(bw[3] >> sh) & 1u) ? 0.f : __expf(s[3]);
            kc0 = kn0; kc1 = kn1;
        }
    }
    rsum += __shfl_xor(rsum, 16);
    rsum += __shfl_xor(rsum, 32);
    const float inv = 1.0f / rsum;

    // ---------- pass 2: recompute -> p -> LDS tile + PV16; coalesced flush per span ----------
    f32x4 o0 = {0.f,0.f,0.f,0.f}, o1 = {0.f,0.f,0.f,0.f};
    f32x4 o2 = {0.f,0.f,0.f,0.f}, o3 = {0.f,0.f,0.f,0.f};
    kc0 = *(const f16x8*)(kpb + l * 8);
    kc1 = *(const f16x8*)(kpb + 512 + l * 8);
    f16x4 bv0 = *(const f16x4*)(vpb + l * 4);
    f16x4 bv1 = *(const f16x4*)(vpb + 256 + l * 4);
    f16x4 bv2 = *(const f16x4*)(vpb + 512 + l * 4);
    f16x4 bv3 = *(const f16x4*)(vpb + 768 + l * 4);
    f16* slw = SL + w * 4096;
    const int swz = (lr & 15) << 2;                   // XOR swizzle for LDS f16-index
    #pragma unroll
    for (int sp = 0; sp < 4; ++sp) {
        const u64x4 bw = bp[sp];
        #pragma unroll
        for (int cc = 0; cc < 16; ++cc) {
            const int c = sp * 16 + cc;
            f16x8 kn0, kn1;
            f16x4 bn0, bn1, bn2, bn3;
            if (c < 63) {
                kn0 = *(const f16x8*)(kpb + (c + 1) * 1024 + l * 8);
                kn1 = *(const f16x8*)(kpb + (c + 1) * 1024 + 512 + l * 8);
                bn0 = *(const f16x4*)(vpb + (c + 1) * 1024 + l * 4);
                bn1 = *(const f16x4*)(vpb + (c + 1) * 1024 + 256 + l * 4);
                bn2 = *(const f16x4*)(vpb + (c + 1) * 1024 + 512 + l * 4);
                bn3 = *(const f16x4*)(vpb + (c + 1) * 1024 + 768 + l * 4);
            }
            f32x4 s = {0.f, 0.f, 0.f, 0.f};
            s = MFMA32(kc0, aq0, s);
            s = MFMA32(kc1, aq1, s);
            const int sh = cc * 4 + lg;
            f16x4 pa;
            pa[0] = (f16)((((unsigned)(bw[0] >> sh) & 1u) ? 0.f : __expf(s[0])) * inv);
            pa[1] = (f16)((((unsigned)(bw[1] >> sh) & 1u) ? 0.f : __expf(s[1])) * inv);
            pa[2] = (f16)((((unsigned)(bw[2] >> sh) & 1u) ? 0.f : __expf(s[2])) * inv);
            pa[3] = (f16)((((unsigned)(bw[3] >> sh) & 1u) ? 0.f : __expf(s[3])) * inv);
            *(f16x4*)&slw[lr * 256 + ((cc * 16 + lg * 4) ^ swz)] = pa;
            o0 = PV16(pa, bv0, o0);
            o1 = PV16(pa, bv1, o1);
            o2 = PV16(pa, bv2, o2);
            o3 = PV16(pa, bv3, o3);
            kc0 = kn0; kc1 = kn1;
            bv0 = bn0; bv1 = bn1; bv2 = bn2; bv3 = bn3;
        }
        // flush span: one full q-row (1 KB contiguous) per store instruction
        asm volatile("s_waitcnt lgkmcnt(0)" ::: "memory");
        __builtin_amdgcn_sched_barrier(0);
        #pragma unroll
        for (int r0 = 0; r0 < 16; ++r0) {
            f16x4 pv = *(const f16x4*)&slw[r0 * 256 + ((l * 4) ^ ((r0 & 15) << 2))];
            f32x4 pf = {(float)pv[0], (float)pv[1], (float)pv[2], (float)pv[3]};
            *(f32x4*)(attn + (size_t)(qbase + r0) * L_ + sp * 256 + l * 4) = pf;
        }
        asm volatile("s_waitcnt lgkmcnt(0)" ::: "memory");
        __builtin_amdgcn_sched_barrier(0);
    }

    // ---------- out: lane holds O[q=lg*4+r][d=nt*16+lr] (already normalized) ----------
    float* op = out + (size_t)(qbase + lg * 4) * D_ + lr;
    #pragma unroll
    for (int r = 0; r < 4; ++r) {
        op[r * D_ + 0]  = o0[r];
        op[r * D_ + 16] = o1[r];
        op[r * D_ + 32] = o2[r];
        op[r * D_ + 48] = o3[r];
    }
}

// ---------------- fallback (round-3 kernel, used if ws too small) ----------------

__device__ __forceinline__ int sidx(int row, int col) {
    return row * 1024 + ((((col >> 3) ^ (row & 7)) << 3) | (col & 7));
}

__global__ __launch_bounds__(256, 4)
void sdpa_fallback(const float* __restrict__ q, const float* __restrict__ kk,
                   const float* __restrict__ v, const unsigned char* __restrict__ mask,
                   float* __restrict__ out, float* __restrict__ attn)
{
    __shared__ f16 S[QT * 1024];
    __shared__ float wmax[4][QT];
    __shared__ float wsum[QT];

    const int tid = threadIdx.x;
    const int l = tid & 63, w = tid >> 6;
    const int lr = l & 15, lg = l >> 4;
    const int bid = blockIdx.x;
    const int b = bid >> 6, qt = bid & 63;
    const int qbase = b * L_ + qt * QT;

    unsigned det = 0;
    {
        const unsigned* mw = (const unsigned*)mask;
        #pragma unroll
        for (int i = 0; i < 32; ++i) det |= mw[i];
    }
    const bool elem4 = (det <= 1u) || (det == 0x3F800000u);

    f16x8 aqh[2], aql[2];
    {
        const float* qp = q + (size_t)(qbase + lr) * D_;
        #pragma unroll
        for (int s = 0; s < 2; ++s) {
            float4 f0 = *(const float4*)(qp + s * 32 + lg * 8);
            float4 f1 = *(const float4*)(qp + s * 32 + lg * 8 + 4);
            float fv[8] = {f0.x, f0.y, f0.z, f0.w, f1.x, f1.y, f1.z, f1.w};
            #pragma unroll
            for (int j = 0; j < 8; ++j) {
                f16 h = (f16)fv[j];
                aqh[s][j] = h;
                aql[s][j] = (f16)(fv[j] - (float)h);
            }
        }
    }

    float vmax[4] = {-INFINITY, -INFINITY, -INFINITY, -INFINITY};
    const float* kb = kk + (size_t)(b * L_ + w * 16 + lr) * D_ + lg * 8;
    const size_t mrowbase = (size_t)(qbase + lg * 4) * L_ + w * 16 + lr;

    float4 kc[4];
    kc[0] = *(const float4*)kb;
    kc[1] = *(const float4*)(kb + 4);
    kc[2] = *(const float4*)(kb + 32);
    kc[3] = *(const float4*)(kb + 36);
    int mcur[4], mnxt[4];
    #pragma unroll
    for (int r2 = 0; r2 < 4; ++r2) {
        if (elem4) {
            mcur[r2] = ((const int*)mask)[mrowbase + (size_t)r2 * L_];
            mnxt[r2] = ((const int*)mask)[mrowbase + (size_t)r2 * L_ + 64];
        } else {
            mcur[r2] = mask[mrowbase + (size_t)r2 * L_];
            mnxt[r2] = mask[mrowbase + (size_t)r2 * L_ + 64];
        }
    }

    for (int ck = 0; ck < 16; ++ck) {
        float4 kn[4];
        if (ck < 15) {
            const float* kp = kb + (size_t)(ck + 1) * 64 * D_;
            kn[0] = *(const float4*)kp;
            kn[1] = *(const float4*)(kp + 4);
            kn[2] = *(const float4*)(kp + 32);
            kn[3] = *(const float4*)(kp + 36);
        }
        int mfut[4];
        if (ck < 14) {
            const size_t mo = mrowbase + (size_t)(ck + 2) * 64;
            if (elem4) {
                #pragma unroll
                for (int r2 = 0; r2 < 4; ++r2) mfut[r2] = ((const int*)mask)[mo + (size_t)r2 * L_];
            } else {
                #pragma unroll
                for (int r2 = 0; r2 < 4; ++r2) mfut[r2] = mask[mo + (size_t)r2 * L_];
            }
        }
        f16x8 bh[2], bl[2];
        #pragma unroll
        for (int s = 0; s < 2; ++s) {
            float fv[8] = {kc[2*s].x, kc[2*s].y, kc[2*s].z, kc[2*s].w,
                           kc[2*s+1].x, kc[2*s+1].y, kc[2*s+1].z, kc[2*s+1].w};
            #pragma unroll
            for (int j = 0; j < 8; ++j) {
                f16 h = (f16)fv[j];
                bh[s][j] = h;
                bl[s][j] = (f16)(fv[j] - (float)h);
            }
        }
        f32x4 acc = {0.f, 0.f, 0.f, 0.f};
        #pragma unroll
        for (int s = 0; s < 2; ++s) {
            acc = MFMA32(aqh[s], bh[s], acc);
            acc = MFMA32(aql[s], bh[s], acc);
            acc = MFMA32(aqh[s], bl[s], acc);
        }
        const int scol = ck * 64 + w * 16 + lr;
        #pragma unroll
        for (int r2 = 0; r2 < 4; ++r2) {
            float sv = mcur[r2] ? -INFINITY : acc[r2] * 0.125f;
            S[sidx(lg * 4 + r2, scol)] = (f16)sv;
            vmax[r2] = fmaxf(vmax[r2], sv);
        }
        #pragma unroll
        for (int r2 = 0; r2 < 4; ++r2) mcur[r2] = mnxt[r2];
        if (ck < 14) {
            #pragma unroll
            for (int r2 = 0; r2 < 4; ++r2) mnxt[r2] = mfut[r2];
        }
        if (ck < 15) {
            #pragma unroll
            for (int j = 0; j < 4; ++j) kc[j] = kn[j];
        }
    }
    #pragma unroll
    for (int r2 = 0; r2 < 4; ++r2) {
        #pragma unroll
        for (int off = 1; off < 16; off <<= 1)
            vmax[r2] = fmaxf(vmax[r2], __shfl_xor(vmax[r2], off));
    }
    if (lr == 0) {
        #pragma unroll
        for (int r2 = 0; r2 < 4; ++r2) wmax[w][lg * 4 + r2] = vmax[r2];
    }
    __syncthreads();

    {
        const int row = tid >> 4, cg = tid & 15;
        const float m = fmaxf(fmaxf(wmax[0][row], wmax[1][row]),
                              fmaxf(wmax[2][row], wmax[3][row]));
        float sum = 0.f;
        #pragma unroll
        for (int c = 0; c < 8; ++c) {
            f16* sp = &S[row * 1024 + (((cg + 16 * c) ^ (row & 7)) << 3)];
            f16x8 sv = *(const f16x8*)sp;
            f16x8 evv;
            #pragma unroll
            for (int j = 0; j < 8; ++j) {
                float e = __expf((float)sv[j] - m);
                evv[j] = (f16)e;
                sum += e;
            }
            *(f16x8*)sp = evv;
        }
        #pragma unroll
        for (int off = 1; off < 16; off <<= 1) sum += __shfl_xor(sum, off);
        if (cg == 0) wsum[row] = sum;
        __syncthreads();

        const float inv = 1.0f / wsum[row];
        float* ap = attn + (size_t)(qbase + row) * L_;
        #pragma unroll
        for (int c = 0; c < 8; ++c) {
            f16x8 evv = *(const f16x8*)&S[row * 1024 + (((cg + 16 * c) ^ (row & 7)) << 3)];
            float4 p0, p1;
            p0.x = (float)evv[0] * inv; p0.y = (float)evv[1] * inv;
            p0.z = (float)evv[2] * inv; p0.w = (float)evv[3] * inv;
            p1.x = (float)evv[4] * inv; p1.y = (float)evv[5] * inv;
            p1.z = (float)evv[6] * inv; p1.w = (float)evv[7] * inv;
            *(float4*)(ap + (cg + 16 * c) * 8)     = p0;
            *(float4*)(ap + (cg + 16 * c) * 8 + 4) = p1;
        }
    }

    f32x4 acc2 = {0.f, 0.f, 0.f, 0.f};
    const float* vb = v + (size_t)(b * L_) * D_ + w * 16 + lr;
    float vcA[8], vcB[8];
    #pragma unroll
    for (int j = 0; j < 8; ++j) {
        vcA[j] = vb[(size_t)(lg * 8 + j) * D_];
        vcB[j] = vb[(size_t)(32 + lg * 8 + j) * D_];
    }
    for (int tt = 0; tt < 16; ++tt) {
        {
            f16x8 pa = *(const f16x8*)&S[lr * 1024 + ((((2 * tt) * 4 + lg) ^ (lr & 7)) << 3)];
            f16x8 bv;
            #pragma unroll
            for (int j = 0; j < 8; ++j) bv[j] = (f16)vcA[j];
            if (tt < 15) {
                const float* vp = vb + (size_t)((2 * tt + 2) * 32 + lg * 8) * D_;
                #pragma unroll
                for (int j = 0; j < 8; ++j) vcA[j] = vp[(size_t)j * D_];
            }
            acc2 = MFMA32(pa, bv, acc2);
        }
        {
            f16x8 pa = *(const f16x8*)&S[lr * 1024 + ((((2 * tt + 1) * 4 + lg) ^ (lr & 7)) << 3)];
            f16x8 bv;
            #pragma unroll
            for (int j = 0; j < 8; ++j) bv[j] = (f16)vcB[j];
            if (tt < 15) {
                const float* vp = vb + (size_t)((2 * tt + 3) * 32 + lg * 8) * D_;
                #pragma unroll
                for (int j = 0; j < 8; ++j) vcB[j] = vp[(size_t)j * D_];
            }
            acc2 = MFMA32(pa, bv, acc2);
        }
    }

    #pragma unroll
    for (int r2 = 0; r2 < 4; ++r2) {
        const float invr = 1.0f / wsum[lg * 4 + r2];
        out[(size_t)(qbase + lg * 4 + r2) * D_ + w * 16 + lr] = acc2[r2] * invr;
    }
}

extern "C" void kernel_launch(void* const* d_in, const int* in_sizes, int n_in,
                              void* d_out, int out_size, void* d_ws, size_t ws_size,
                              hipStream_t stream) {
    const float* q = (const float*)d_in[0];
    const float* k = (const float*)d_in[1];
    const float* v = (const float*)d_in[2];
    const unsigned char* mask = (const unsigned char*)d_in[3];
    float* out = (float*)d_out;
    float* attn = out + (size_t)B_ * L_ * D_;

    if (ws_size >= (size_t)WS_NEED) {
        f16* kpack = (f16*)((char*)d_ws + WS_KP);
        f16* vpack = (f16*)((char*)d_ws + WS_VP);
        u64* bits = (u64*)((char*)d_ws + WS_BT);
        mega_prep<<<dim3(5120), 256, 0, stream>>>(k, v, mask, kpack, vpack, bits);
        sdpa_main<<<dim3(1024), 256, 0, stream>>>(q, kpack, vpack, bits, out, attn);
    } else {
        sdpa_fallback<<<dim3(B_ * (L_ / QT)), 256, 0, stream>>>(q, k, v, mask, out, attn);
    }
}